// Round 1
// baseline (1101.325 us; speedup 1.0000x reference)
//
#include <hip/hip_runtime.h>
#include <math.h>

// Problem constants
#define HH 200
#define WW 200
#define CIN 256
#define OMCH 108   // 72 offset + 36 mask
#define OCH 256
#define NPIX (HH*WW)

typedef __bf16 bf16x8 __attribute__((ext_vector_type(8)));
typedef float floatx4 __attribute__((ext_vector_type(4)));

static __device__ __forceinline__ unsigned short bf16bits(float v) {
    __bf16 h = (__bf16)v;
    return __builtin_bit_cast(unsigned short, h);
}
static __device__ __forceinline__ float lo_bf(unsigned int u) {
    return __builtin_bit_cast(float, u << 16);
}
static __device__ __forceinline__ float hi_bf(unsigned int u) {
    return __builtin_bit_cast(float, u & 0xffff0000u);
}

// ---------------------------------------------------------------------------
// P0: x [B][C][HW] fp32 -> xT [B][HW][C] bf16.  64-pixel tiles, LDS transpose.
__global__ __launch_bounds__(256) void transpose_x(const float* __restrict__ x,
                                                   unsigned short* __restrict__ xT) {
    __shared__ __align__(16) unsigned short st[64][264];
    int t = threadIdx.x;
    int blk = blockIdx.x;                 // 2 * 625
    int b = blk / 625, pix0 = (blk % 625) * 64;
    const float* xb = x + (size_t)b * CIN * NPIX + pix0;
    int p = t & 63, oct = t >> 6;

    for (int c32 = 0; c32 < CIN; c32 += 32) {
        int c = c32 + oct * 8;
        union { unsigned short u[8]; float4 f; } pk;
#pragma unroll
        for (int i = 0; i < 8; i++)
            pk.u[i] = bf16bits(xb[(size_t)(c + i) * NPIX + p]);
        *(float4*)&st[p][c] = pk.f;
    }
    __syncthreads();
    int p2 = t >> 2, qo = t & 3;
    unsigned short* dst = xT + ((size_t)b * NPIX + pix0 + p2) * CIN + qo * 64;
#pragma unroll
    for (int j = 0; j < 8; j++)
        *(float4*)(dst + j * 8) = *(const float4*)&st[p2][qo * 64 + j * 8];
}

// ---------------------------------------------------------------------------
// P1: w_om [108][256][3][3] fp32 -> wom2 bf16 [128 padded oc][klin], klin = tap*256 + c
__global__ void prep_wom(const float* __restrict__ w, unsigned short* __restrict__ wom2) {
    int i = blockIdx.x * 256 + threadIdx.x;   // i < 128*2304
    int oc = i / 2304, klin = i % 2304;
    int tap = klin >> 8, c = klin & 255;
    float v = (oc < OMCH) ? w[(size_t)oc * 2304 + c * 9 + tap] : 0.f;
    wom2[i] = bf16bits(v);
}

// P2: w_dcn [256][256][3][3] fp32 -> wt2 bf16 [oc][klin], klin = (g*9+k)*64 + c
__global__ void prep_wdcn(const float* __restrict__ w, unsigned short* __restrict__ wt2) {
    int i = blockIdx.x * 256 + threadIdx.x;   // i < 256*2304
    int oc = i / 2304, klin = i % 2304;
    int gk = klin >> 6, c = klin & 63;
    int g = gk / 9, kk = gk % 9;
    wt2[i] = bf16bits(w[(size_t)oc * 2304 + (g * 64 + c) * 9 + kk]);
}

// ---------------------------------------------------------------------------
// K1: om conv via bf16 MFMA. 512 thr / 8 waves, 128 px/block.
// Waves: (wv&3) -> oc quarter, (wv>>2) -> pixel half (64 px each).
// 36 iters: tap (9) x 64-ch chunk (4). 2-deep staging pipeline (sets A/B),
// XOR-swizzled vbuf (no pad), setprio around MFMA cluster.
__global__ __launch_bounds__(512, 6) void om_mfma(const unsigned short* __restrict__ xT,
                                                  const unsigned short* __restrict__ wom2,
                                                  const float* __restrict__ bom,
                                                  float* __restrict__ om) {
    __shared__ __align__(16) unsigned short vbuf[2][128][64];  // 32768 B, XOR-swizzled 16B units

    int t = threadIdx.x;
    int p4 = t >> 2;                      // staging pixel 0..127
    int c4 = t & 3;                       // staging chunk 0..3
    int lane = t & 63, n16 = t & 15, quad = lane >> 4, wv = t >> 6;
    int ocbase = (wv & 3) * 32;
    int ph = (wv >> 2) * 64;
    int m7 = (n16 & 7) * 8;               // read-side swizzle (rows are n16 mod 8 aligned)
    int suA8 = (c4 ^ (p4 & 7)) * 8;       // write-side swizzle: unit c4
    int suB8 = ((c4 + 4) ^ (p4 & 7)) * 8; // write-side swizzle: unit c4+4

    int gp0 = blockIdx.x * 128;           // 625 blocks over 80000 flat pixels
    int sp = gp0 + p4;                    // staging flat pixel (may straddle batch)
    int sb = (sp >= NPIX) ? 1 : 0;
    int srem = sp - sb * NPIX;
    int sh = srem / WW, sw = srem % WW;
    const unsigned short* xtb = xT + (size_t)sb * NPIX * CIN;

    floatx4 acc[2][4];
#pragma unroll
    for (int i = 0; i < 2; i++)
#pragma unroll
        for (int j = 0; j < 4; j++) acc[i][j] = (floatx4){0.f, 0.f, 0.f, 0.f};

#define OM_ISSUE(FA, FB, ITN)                                                   \
    do {                                                                        \
        int tap_ = (ITN) >> 2, c0_ = ((ITN) & 3) << 6;                          \
        int h2_ = sh + tap_ / 3 - 1, w2_ = sw + tap_ % 3 - 1;                   \
        FA = (float4){0.f, 0.f, 0.f, 0.f};                                      \
        FB = (float4){0.f, 0.f, 0.f, 0.f};                                      \
        if (((unsigned)h2_ < (unsigned)HH) && ((unsigned)w2_ < (unsigned)WW)) { \
            const unsigned short* src_ =                                        \
                xtb + (size_t)(h2_ * WW + w2_) * CIN + c0_ + c4 * 8;            \
            FA = *(const float4*)src_;                                          \
            FB = *(const float4*)(src_ + 32);                                   \
        }                                                                       \
    } while (0)

#define OM_WRITE(FA, FB, DSTBUF)                                                \
    do {                                                                        \
        *(float4*)&vbuf[DSTBUF][p4][suA8] = FA;                                 \
        *(float4*)&vbuf[DSTBUF][p4][suB8] = FB;                                 \
    } while (0)

#define OM_MFMA_PHASE(BUF, IT)                                                  \
    do {                                                                        \
        int tap_ = (IT) >> 2, c0_ = ((IT) & 3) << 6;                            \
        const unsigned short* wb_ = wom2 + (size_t)(tap_ * 256 + c0_) + quad * 8; \
        __builtin_amdgcn_s_setprio(1);                                          \
        _Pragma("unroll")                                                       \
        for (int ks = 0; ks < 2; ks++) {                                        \
            int u8_ = ((ks * 4 + quad) * 8) ^ m7;                               \
            bf16x8 bf0 = *(const bf16x8*)&vbuf[BUF][ph + n16     ][u8_];        \
            bf16x8 bf1 = *(const bf16x8*)&vbuf[BUF][ph + 16 + n16][u8_];        \
            bf16x8 bf2 = *(const bf16x8*)&vbuf[BUF][ph + 32 + n16][u8_];        \
            bf16x8 bf3 = *(const bf16x8*)&vbuf[BUF][ph + 48 + n16][u8_];        \
            _Pragma("unroll")                                                   \
            for (int oi = 0; oi < 2; oi++) {                                    \
                bf16x8 a = *(const bf16x8*)&wb_[(size_t)(ocbase + oi * 16 + n16) * 2304 + ks * 32]; \
                acc[oi][0] = __builtin_amdgcn_mfma_f32_16x16x32_bf16(a, bf0, acc[oi][0], 0, 0, 0); \
                acc[oi][1] = __builtin_amdgcn_mfma_f32_16x16x32_bf16(a, bf1, acc[oi][1], 0, 0, 0); \
                acc[oi][2] = __builtin_amdgcn_mfma_f32_16x16x32_bf16(a, bf2, acc[oi][2], 0, 0, 0); \
                acc[oi][3] = __builtin_amdgcn_mfma_f32_16x16x32_bf16(a, bf3, acc[oi][3], 0, 0, 0); \
            }                                                                   \
        }                                                                       \
        __builtin_amdgcn_s_setprio(0);                                          \
    } while (0)

    // ---- pipeline prologue: A = it0, B = it1 (both tap 0) ----
    float4 faA, fbA, faB, fbB;
    OM_ISSUE(faA, fbA, 0);
    OM_ISSUE(faB, fbB, 1);
    OM_WRITE(faA, fbA, 0);
    __syncthreads();

#pragma unroll 1
    for (int it = 0; it < 36; it += 2) {
        // ---- even iter: compute it, write it+1 (set B), load it+2 (set A) ----
        if (it + 2 < 36) OM_ISSUE(faA, fbA, it + 2);
        __builtin_amdgcn_sched_barrier(0);
        OM_MFMA_PHASE(0, it);
        OM_WRITE(faB, fbB, 1);
        __syncthreads();
        // ---- odd iter: compute it+1, write it+2 (set A), load it+3 (set B) ----
        if (it + 3 < 36) OM_ISSUE(faB, fbB, it + 3);
        __builtin_amdgcn_sched_barrier(0);
        OM_MFMA_PHASE(1, it + 1);
        if (it + 2 < 36) {
            OM_WRITE(faA, fbA, 0);
            __syncthreads();
        }
    }

    // epilogue: D col = n16 (pixel), row = quad*4+r (oc); + bias
#pragma unroll
    for (int oi = 0; oi < 2; oi++) {
        int oc0 = ocbase + oi * 16 + quad * 4;
        if (oc0 < OMCH) {
#pragma unroll
            for (int pt = 0; pt < 4; pt++) {
                int fp = gp0 + ph + pt * 16 + n16;
                int bq = (fp >= NPIX) ? 1 : 0;
                int rem = fp - bq * NPIX;
#pragma unroll
                for (int r = 0; r < 4; r++) {
                    int occ = oc0 + r;
                    if (occ < OMCH)
                        om[((size_t)(bq * OMCH + occ)) * NPIX + rem] = acc[oi][pt][r] + bom[occ];
                }
            }
        }
    }
#undef OM_ISSUE
#undef OM_WRITE
#undef OM_MFMA_PHASE
}

// ---------------------------------------------------------------------------
// K2: fused DCN. 512 thr / 8 waves, 64 px/block. Wave wv -> oc [32wv, +32).
// 2-deep gather pipeline: loads for gk+2 issued at gk, packed at gk+1.
// XOR-swizzled vbuf (no pad). setprio around MFMA cluster.
__global__ __launch_bounds__(512, 6) void dcn_mfma(const unsigned short* __restrict__ xT,
                                                   const float* __restrict__ om,
                                                   const unsigned short* __restrict__ wt2,
                                                   float* __restrict__ out) {
    __shared__ unsigned int iPk[36 * 64];                    //  9216 B: i00 | dx1<<16 | dy1<<17
    __shared__ uint2        wPk[36 * 64];                    // 18432 B: 4 x bf16 corner weights
    __shared__ __align__(16) unsigned short vbuf[2][64][64]; // 16384 B, XOR-swizzled 16B units

    int t = threadIdx.x;
    int l = t & 63;
    int oct = t >> 6;             // wave id
    int p8 = l >> 3;              // pixel sub-index within wave
    int chunk = l & 7;            // 16B channel chunk
    int mypix = oct * 8 + p8;     // staging pixel 0..63
    int n16 = t & 15, quad = l >> 4;
    int ocbase = oct * 32;
    int m7 = (n16 & 7) * 8;                 // read-side swizzle
    int swz_w8 = (chunk ^ (mypix & 7)) * 8; // write-side swizzle

    int gp0 = blockIdx.x * 64;    // 1250 blocks; 40000 % 64 == 0, no batch straddle
    int b = gp0 / NPIX;
    int pix0 = gp0 - b * NPIX;
    const unsigned short* xtb = xT + (size_t)b * NPIX * CIN;
    const float* omb = om + (size_t)b * OMCH * NPIX;

    // ---- prologue: packed sampling params for all (gk, p) ----
    for (int r = t; r < 36 * 64; r += 512) {
        int gk = r >> 6, p = r & 63;
        int g = gk / 9, kk = gk % 9;
        int ki = kk / 3, kj = kk % 3;
        int pp = pix0 + p;
        int hh = pp / WW, ww2 = pp % WW;
        float dy = omb[(size_t)(g * 18 + 2 * kk    ) * NPIX + pp];
        float dx = omb[(size_t)(g * 18 + 2 * kk + 1) * NPIX + pp];
        float mr = omb[(size_t)(72 + g * 9 + kk    ) * NPIX + pp];
        float m = 1.f / (1.f + __expf(-mr));
        float py = (float)(hh - 1 + ki) + dy;
        float px = (float)(ww2 - 1 + kj) + dx;
        float fy = floorf(py), fx = floorf(px);
        float wy = py - fy, wx = px - fx;
        int y0 = (int)fy, x0 = (int)fx, y1 = y0 + 1, x1 = x0 + 1;
        bool vy0 = (y0 >= 0) && (y0 < HH), vy1 = (y1 >= 0) && (y1 < HH);
        bool vx0 = (x0 >= 0) && (x0 < WW), vx1 = (x1 >= 0) && (x1 < WW);
        int cy0 = min(max(y0, 0), HH - 1), cy1 = min(max(y1, 0), HH - 1);
        int cx0 = min(max(x0, 0), WW - 1), cx1 = min(max(x1, 0), WW - 1);
        float w00 = (vy0 && vx0) ? (1.f - wy) * (1.f - wx) * m : 0.f;
        float w01 = (vy0 && vx1) ? (1.f - wy) * wx * m : 0.f;
        float w10 = (vy1 && vx0) ? wy * (1.f - wx) * m : 0.f;
        float w11 = (vy1 && vx1) ? wy * wx * m : 0.f;
        int i00 = cy0 * WW + cx0;
        unsigned int dx1 = (unsigned int)(cx1 - cx0);   // 0/1
        unsigned int dy1 = (unsigned int)(cy1 - cy0);   // 0/1
        iPk[r] = (unsigned int)i00 | (dx1 << 16) | (dy1 << 17);
        uint2 wp;
        wp.x = (unsigned int)bf16bits(w00) | ((unsigned int)bf16bits(w01) << 16);
        wp.y = (unsigned int)bf16bits(w10) | ((unsigned int)bf16bits(w11) << 16);
        wPk[r] = wp;
    }
    __syncthreads();

    floatx4 acc[2][4];
#pragma unroll
    for (int i = 0; i < 2; i++)
#pragma unroll
        for (int j = 0; j < 4; j++) acc[i][j] = (floatx4){0.f, 0.f, 0.f, 0.f};

    unsigned int ipNext; uint2 wpNext;

#define DCN_PRELOAD(GKN)                                                        \
    do {                                                                        \
        ipNext = iPk[(GKN) * 64 + mypix];                                       \
        wpNext = wPk[(GKN) * 64 + mypix];                                       \
    } while (0)

#define DCN_ISSUE(C00, C01, C10, C11, SWP, GKN)                                 \
    do {                                                                        \
        unsigned int ip_ = ipNext; SWP = wpNext;                                \
        int i00_ = ip_ & 0xffff;                                                \
        int dx1_ = (ip_ >> 16) & 1, dy1_ = (ip_ >> 17) & 1;                     \
        int i01_ = i00_ + dx1_, i10_ = i00_ + dy1_ * WW, i11_ = i10_ + dx1_;    \
        const unsigned short* xg_ = xtb + ((GKN) / 9) * 64 + chunk * 8;         \
        C00 = *(const bf16x8*)(xg_ + (size_t)i00_ * CIN);                       \
        C01 = *(const bf16x8*)(xg_ + (size_t)i01_ * CIN);                       \
        C10 = *(const bf16x8*)(xg_ + (size_t)i10_ * CIN);                       \
        C11 = *(const bf16x8*)(xg_ + (size_t)i11_ * CIN);                       \
    } while (0)

#define DCN_PACK(C00, C01, C10, C11, SWP, DSTBUF)                               \
    do {                                                                        \
        float w00_ = lo_bf(SWP.x), w01_ = hi_bf(SWP.x);                         \
        float w10_ = lo_bf(SWP.y), w11_ = hi_bf(SWP.y);                         \
        union { unsigned short u[8]; float4 f; } pk_;                           \
        _Pragma("unroll")                                                       \
        for (int i = 0; i < 8; i++) {                                           \
            float v_ = w00_ * (float)C00[i] + w01_ * (float)C01[i]              \
                     + w10_ * (float)C10[i] + w11_ * (float)C11[i];             \
            pk_.u[i] = bf16bits(v_);                                            \
        }                                                                       \
        *(float4*)&vbuf[DSTBUF][mypix][swz_w8] = pk_.f;                         \
    } while (0)

#define DCN_MFMA_PHASE(BUF, GKI)                                                \
    do {                                                                        \
        const unsigned short* wb_ = wt2 + (GKI) * 64 + quad * 8;                \
        __builtin_amdgcn_s_setprio(1);                                          \
        _Pragma("unroll")                                                       \
        for (int ks = 0; ks < 2; ks++) {                                        \
            int u8_ = ((ks * 4 + quad) * 8) ^ m7;                               \
            bf16x8 bf0 = *(const bf16x8*)&vbuf[BUF][n16     ][u8_];             \
            bf16x8 bf1 = *(const bf16x8*)&vbuf[BUF][16 + n16][u8_];             \
            bf16x8 bf2 = *(const bf16x8*)&vbuf[BUF][32 + n16][u8_];             \
            bf16x8 bf3 = *(const bf16x8*)&vbuf[BUF][48 + n16][u8_];             \
            _Pragma("unroll")                                                   \
            for (int oi = 0; oi < 2; oi++) {                                    \
                bf16x8 a = *(const bf16x8*)&wb_[(size_t)(ocbase + oi * 16 + n16) * 2304 + ks * 32]; \
                acc[oi][0] = __builtin_amdgcn_mfma_f32_16x16x32_bf16(a, bf0, acc[oi][0], 0, 0, 0); \
                acc[oi][1] = __builtin_amdgcn_mfma_f32_16x16x32_bf16(a, bf1, acc[oi][1], 0, 0, 0); \
                acc[oi][2] = __builtin_amdgcn_mfma_f32_16x16x32_bf16(a, bf2, acc[oi][2], 0, 0, 0); \
                acc[oi][3] = __builtin_amdgcn_mfma_f32_16x16x32_bf16(a, bf3, acc[oi][3], 0, 0, 0); \
            }                                                                   \
        }                                                                       \
        __builtin_amdgcn_s_setprio(0);                                          \
    } while (0)

    // ---- pipeline prologue: A = gk0 (packed -> vbuf[0]), B = gk1 in regs ----
    bf16x8 a00, a01, a10, a11, b00, b01, b10, b11;
    uint2 wpA, wpB;
    DCN_PRELOAD(0);
    DCN_ISSUE(a00, a01, a10, a11, wpA, 0);
    DCN_PRELOAD(1);
    DCN_ISSUE(b00, b01, b10, b11, wpB, 1);
    DCN_PRELOAD(2);
    DCN_PACK(a00, a01, a10, a11, wpA, 0);
    __syncthreads();

#pragma unroll 1
    for (int gk = 0; gk < 36; gk += 2) {
        // ---- even iter: compute gk, pack gk+1 (set B), load gk+2 (set A) ----
        if (gk + 2 < 36) DCN_ISSUE(a00, a01, a10, a11, wpA, gk + 2);
        if (gk + 3 < 36) DCN_PRELOAD(gk + 3);
        __builtin_amdgcn_sched_barrier(0);
        DCN_MFMA_PHASE(0, gk);
        DCN_PACK(b00, b01, b10, b11, wpB, 1);
        __syncthreads();
        // ---- odd iter: compute gk+1, pack gk+2 (set A), load gk+3 (set B) ----
        if (gk + 3 < 36) DCN_ISSUE(b00, b01, b10, b11, wpB, gk + 3);
        if (gk + 4 < 36) DCN_PRELOAD(gk + 4);
        __builtin_amdgcn_sched_barrier(0);
        DCN_MFMA_PHASE(1, gk + 1);
        if (gk + 2 < 36) {
            DCN_PACK(a00, a01, a10, a11, wpA, 0);
            __syncthreads();
        }
    }

    // ---- epilogue: ReLU + store ----
#pragma unroll
    for (int oi = 0; oi < 2; oi++)
#pragma unroll
        for (int pt = 0; pt < 4; pt++) {
            int gpix = pix0 + pt * 16 + n16;
#pragma unroll
            for (int r = 0; r < 4; r++) {
                int oc = ocbase + oi * 16 + quad * 4 + r;
                out[((size_t)(b * OCH + oc)) * NPIX + gpix] = fmaxf(acc[oi][pt][r], 0.f);
            }
        }
#undef DCN_PRELOAD
#undef DCN_ISSUE
#undef DCN_PACK
#undef DCN_MFMA_PHASE
}

// ---------------------------------------------------------------------------
extern "C" void kernel_launch(void* const* d_in, const int* in_sizes, int n_in,
                              void* d_out, int out_size, void* d_ws, size_t ws_size,
                              hipStream_t stream) {
    const float* x     = (const float*)d_in[0];
    const float* w_om  = (const float*)d_in[1];
    const float* b_om  = (const float*)d_in[2];
    const float* w_dcn = (const float*)d_in[3];
    float* out = (float*)d_out;

    // workspace layout (77.3 MB total)
    char* ws = (char*)d_ws;
    float*          om   = (float*)(ws);                         // 34,560,000 B
    unsigned short* xT   = (unsigned short*)(ws + 34560000);     // 40,960,000 B
    unsigned short* wom2 = (unsigned short*)(ws + 75520000);     //    589,824 B
    unsigned short* wt2  = (unsigned short*)(ws + 76109824);     //  1,179,648 B

    transpose_x<<<1250, 256, 0, stream>>>(x, xT);
    prep_wom   <<<1152, 256, 0, stream>>>(w_om, wom2);
    prep_wdcn  <<<2304, 256, 0, stream>>>(w_dcn, wt2);
    om_mfma    <<< 625, 512, 0, stream>>>(xT, wom2, b_om, om);
    dcn_mfma   <<<1250, 512, 0, stream>>>(xT, om, wt2, out);
}

// Round 2
// 1090.981 us; speedup vs baseline: 1.0095x; 1.0095x over previous
//
#include <hip/hip_runtime.h>
#include <math.h>

// Problem constants
#define HH 200
#define WW 200
#define CIN 256
#define OMCH 108   // 72 offset + 36 mask
#define OCH 256
#define NPIX (HH*WW)

typedef __bf16 bf16x8 __attribute__((ext_vector_type(8)));
typedef float floatx4 __attribute__((ext_vector_type(4)));

static __device__ __forceinline__ unsigned short bf16bits(float v) {
    __bf16 h = (__bf16)v;
    return __builtin_bit_cast(unsigned short, h);
}
static __device__ __forceinline__ float lo_bf(unsigned int u) {
    return __builtin_bit_cast(float, u << 16);
}
static __device__ __forceinline__ float hi_bf(unsigned int u) {
    return __builtin_bit_cast(float, u & 0xffff0000u);
}

// ---------------------------------------------------------------------------
// P0: x [B][C][HW] fp32 -> xT [B][HW][C] bf16.  64-pixel tiles, LDS transpose.
__global__ __launch_bounds__(256) void transpose_x(const float* __restrict__ x,
                                                   unsigned short* __restrict__ xT) {
    __shared__ __align__(16) unsigned short st[64][264];
    int t = threadIdx.x;
    int blk = blockIdx.x;                 // 2 * 625
    int b = blk / 625, pix0 = (blk % 625) * 64;
    const float* xb = x + (size_t)b * CIN * NPIX + pix0;
    int p = t & 63, oct = t >> 6;

    for (int c32 = 0; c32 < CIN; c32 += 32) {
        int c = c32 + oct * 8;
        union { unsigned short u[8]; float4 f; } pk;
#pragma unroll
        for (int i = 0; i < 8; i++)
            pk.u[i] = bf16bits(xb[(size_t)(c + i) * NPIX + p]);
        *(float4*)&st[p][c] = pk.f;
    }
    __syncthreads();
    int p2 = t >> 2, qo = t & 3;
    unsigned short* dst = xT + ((size_t)b * NPIX + pix0 + p2) * CIN + qo * 64;
#pragma unroll
    for (int j = 0; j < 8; j++)
        *(float4*)(dst + j * 8) = *(const float4*)&st[p2][qo * 64 + j * 8];
}

// ---------------------------------------------------------------------------
// P1: w_om [108][256][3][3] fp32 -> wom2 bf16 [128 padded oc][klin], klin = tap*256 + c
__global__ void prep_wom(const float* __restrict__ w, unsigned short* __restrict__ wom2) {
    int i = blockIdx.x * 256 + threadIdx.x;   // i < 128*2304
    int oc = i / 2304, klin = i % 2304;
    int tap = klin >> 8, c = klin & 255;
    float v = (oc < OMCH) ? w[(size_t)oc * 2304 + c * 9 + tap] : 0.f;
    wom2[i] = bf16bits(v);
}

// P2: w_dcn [256][256][3][3] fp32 -> wt2 bf16 [oc][klin], klin = (g*9+k)*64 + c
__global__ void prep_wdcn(const float* __restrict__ w, unsigned short* __restrict__ wt2) {
    int i = blockIdx.x * 256 + threadIdx.x;   // i < 256*2304
    int oc = i / 2304, klin = i % 2304;
    int gk = klin >> 6, c = klin & 63;
    int g = gk / 9, kk = gk % 9;
    wt2[i] = bf16bits(w[(size_t)oc * 2304 + (g * 64 + c) * 9 + kk]);
}

// ---------------------------------------------------------------------------
// K1: om conv via bf16 MFMA. 512 thr / 8 waves, 128 px/block.
// Waves: (wv&3) -> oc quarter, (wv>>2) -> pixel half (64 px each).
// 36 iters: tap (9) x 64-ch chunk (4); 1-deep pipeline (regs live only within
// one iteration -> no spills), XOR-swizzled vbuf (0 bank conflicts), setprio.
__global__ __launch_bounds__(512, 6) void om_mfma(const unsigned short* __restrict__ xT,
                                                  const unsigned short* __restrict__ wom2,
                                                  const float* __restrict__ bom,
                                                  float* __restrict__ om) {
    __shared__ __align__(16) unsigned short vbuf[2][128][64];  // 32768 B, XOR-swizzled 16B units

    int t = threadIdx.x;
    int p4 = t >> 2;                      // staging pixel 0..127
    int c4 = t & 3;                       // staging chunk 0..3
    int lane = t & 63, n16 = t & 15, quad = lane >> 4, wv = t >> 6;
    int ocbase = (wv & 3) * 32;
    int ph = (wv >> 2) * 64;
    int m7 = (n16 & 7) * 8;               // read-side swizzle (row&7 == n16&7)
    int suA8 = (c4 ^ (p4 & 7)) * 8;       // write-side swizzle: unit c4
    int suB8 = ((c4 + 4) ^ (p4 & 7)) * 8; // write-side swizzle: unit c4+4

    int gp0 = blockIdx.x * 128;           // 625 blocks over 80000 flat pixels
    int sp = gp0 + p4;                    // staging flat pixel (may straddle batch)
    int sb = (sp >= NPIX) ? 1 : 0;
    int srem = sp - sb * NPIX;
    int sh = srem / WW, sw = srem % WW;
    const unsigned short* xtb = xT + (size_t)sb * NPIX * CIN;

    floatx4 acc[2][4];
#pragma unroll
    for (int i = 0; i < 2; i++)
#pragma unroll
        for (int j = 0; j < 4; j++) acc[i][j] = (floatx4){0.f, 0.f, 0.f, 0.f};

    // stage it=0 (tap 0: di=-1,dj=-1; c0=0)
    {
        int h2 = sh - 1, w2 = sw - 1;
        bool valid = ((unsigned)h2 < (unsigned)HH) && ((unsigned)w2 < (unsigned)WW);
        float4 fa = {0.f,0.f,0.f,0.f}, fb = {0.f,0.f,0.f,0.f};
        if (valid) {
            const unsigned short* src = xtb + (size_t)(h2 * WW + w2) * CIN + c4 * 8;
            fa = *(const float4*)src;
            fb = *(const float4*)(src + 32);
        }
        *(float4*)&vbuf[0][p4][suA8] = fa;
        *(float4*)&vbuf[0][p4][suB8] = fb;
    }
    __syncthreads();

    for (int it = 0; it < 36; it++) {
        int tap = it >> 2, c0 = (it & 3) << 6;
        int cur = it & 1;
        bool have = (it < 35);

        // --- prefetch next staging chunk into registers (consumed this iter) ---
        float4 nfa = {0.f,0.f,0.f,0.f}, nfb = {0.f,0.f,0.f,0.f};
        if (have) {
            int itn = it + 1;
            int tapn = itn >> 2, c0n = (itn & 3) << 6;
            int h2 = sh + tapn / 3 - 1, w2 = sw + tapn % 3 - 1;
            bool valid = ((unsigned)h2 < (unsigned)HH) && ((unsigned)w2 < (unsigned)WW);
            if (valid) {
                const unsigned short* src = xtb + (size_t)(h2 * WW + w2) * CIN + c0n + c4 * 8;
                nfa = *(const float4*)src;
                nfb = *(const float4*)(src + 32);
            }
        }

        // --- MFMA phase ---
        const unsigned short* wb = wom2 + (size_t)(tap * 256 + c0) + quad * 8;
        __builtin_amdgcn_s_setprio(1);
#pragma unroll
        for (int ks = 0; ks < 2; ks++) {
            int u8 = ((ks * 4 + quad) * 8) ^ m7;
            bf16x8 bf0 = *(const bf16x8*)&vbuf[cur][ph + n16     ][u8];
            bf16x8 bf1 = *(const bf16x8*)&vbuf[cur][ph + 16 + n16][u8];
            bf16x8 bf2 = *(const bf16x8*)&vbuf[cur][ph + 32 + n16][u8];
            bf16x8 bf3 = *(const bf16x8*)&vbuf[cur][ph + 48 + n16][u8];
#pragma unroll
            for (int oi = 0; oi < 2; oi++) {
                bf16x8 a = *(const bf16x8*)&wb[(size_t)(ocbase + oi * 16 + n16) * 2304 + ks * 32];
                acc[oi][0] = __builtin_amdgcn_mfma_f32_16x16x32_bf16(a, bf0, acc[oi][0], 0, 0, 0);
                acc[oi][1] = __builtin_amdgcn_mfma_f32_16x16x32_bf16(a, bf1, acc[oi][1], 0, 0, 0);
                acc[oi][2] = __builtin_amdgcn_mfma_f32_16x16x32_bf16(a, bf2, acc[oi][2], 0, 0, 0);
                acc[oi][3] = __builtin_amdgcn_mfma_f32_16x16x32_bf16(a, bf3, acc[oi][3], 0, 0, 0);
            }
        }
        __builtin_amdgcn_s_setprio(0);

        if (have) {
            *(float4*)&vbuf[cur ^ 1][p4][suA8] = nfa;
            *(float4*)&vbuf[cur ^ 1][p4][suB8] = nfb;
            __syncthreads();
        }
    }

    // epilogue: D col = n16 (pixel), row = quad*4+r (oc); + bias
#pragma unroll
    for (int oi = 0; oi < 2; oi++) {
        int oc0 = ocbase + oi * 16 + quad * 4;
        if (oc0 < OMCH) {
#pragma unroll
            for (int pt = 0; pt < 4; pt++) {
                int fp = gp0 + ph + pt * 16 + n16;
                int bq = (fp >= NPIX) ? 1 : 0;
                int rem = fp - bq * NPIX;
#pragma unroll
                for (int r = 0; r < 4; r++) {
                    int occ = oc0 + r;
                    if (occ < OMCH)
                        om[((size_t)(bq * OMCH + occ)) * NPIX + rem] = acc[oi][pt][r] + bom[occ];
                }
            }
        }
    }
}

// ---------------------------------------------------------------------------
// K2: fused DCN. 512 thr / 8 waves, 64 px/block. Wave wv -> oc [32wv, +32).
// 1-deep pipeline: parm(gk+2) LDS-read || gather(gk+1) || MFMA(gk) || pack(gk+1).
// XOR-swizzled vbuf (0 bank conflicts), setprio around MFMA cluster.
__global__ __launch_bounds__(512, 6) void dcn_mfma(const unsigned short* __restrict__ xT,
                                                   const float* __restrict__ om,
                                                   const unsigned short* __restrict__ wt2,
                                                   float* __restrict__ out) {
    __shared__ unsigned int iPk[36 * 64];                    //  9216 B: i00 | dx1<<16 | dy1<<17
    __shared__ uint2        wPk[36 * 64];                    // 18432 B: 4 x bf16 corner weights
    __shared__ __align__(16) unsigned short vbuf[2][64][64]; // 16384 B, XOR-swizzled 16B units

    int t = threadIdx.x;
    int l = t & 63;
    int oct = t >> 6;             // wave id
    int p8 = l >> 3;              // pixel sub-index within wave
    int chunk = l & 7;            // 16B channel chunk
    int mypix = oct * 8 + p8;     // staging pixel 0..63
    int n16 = t & 15, quad = l >> 4;
    int ocbase = oct * 32;
    int m7 = (n16 & 7) * 8;                 // read-side swizzle
    int swz_w8 = (chunk ^ (mypix & 7)) * 8; // write-side swizzle

    int gp0 = blockIdx.x * 64;    // 1250 blocks; 40000 % 64 == 0, no batch straddle
    int b = gp0 / NPIX;
    int pix0 = gp0 - b * NPIX;
    const unsigned short* xtb = xT + (size_t)b * NPIX * CIN;
    const float* omb = om + (size_t)b * OMCH * NPIX;

    // ---- prologue: packed sampling params for all (gk, p) ----
    for (int r = t; r < 36 * 64; r += 512) {
        int gk = r >> 6, p = r & 63;
        int g = gk / 9, kk = gk % 9;
        int ki = kk / 3, kj = kk % 3;
        int pp = pix0 + p;
        int hh = pp / WW, ww2 = pp % WW;
        float dy = omb[(size_t)(g * 18 + 2 * kk    ) * NPIX + pp];
        float dx = omb[(size_t)(g * 18 + 2 * kk + 1) * NPIX + pp];
        float mr = omb[(size_t)(72 + g * 9 + kk    ) * NPIX + pp];
        float m = 1.f / (1.f + __expf(-mr));
        float py = (float)(hh - 1 + ki) + dy;
        float px = (float)(ww2 - 1 + kj) + dx;
        float fy = floorf(py), fx = floorf(px);
        float wy = py - fy, wx = px - fx;
        int y0 = (int)fy, x0 = (int)fx, y1 = y0 + 1, x1 = x0 + 1;
        bool vy0 = (y0 >= 0) && (y0 < HH), vy1 = (y1 >= 0) && (y1 < HH);
        bool vx0 = (x0 >= 0) && (x0 < WW), vx1 = (x1 >= 0) && (x1 < WW);
        int cy0 = min(max(y0, 0), HH - 1), cy1 = min(max(y1, 0), HH - 1);
        int cx0 = min(max(x0, 0), WW - 1), cx1 = min(max(x1, 0), WW - 1);
        float w00 = (vy0 && vx0) ? (1.f - wy) * (1.f - wx) * m : 0.f;
        float w01 = (vy0 && vx1) ? (1.f - wy) * wx * m : 0.f;
        float w10 = (vy1 && vx0) ? wy * (1.f - wx) * m : 0.f;
        float w11 = (vy1 && vx1) ? wy * wx * m : 0.f;
        int i00 = cy0 * WW + cx0;
        unsigned int dx1 = (unsigned int)(cx1 - cx0);   // 0/1
        unsigned int dy1 = (unsigned int)(cy1 - cy0);   // 0/1
        iPk[r] = (unsigned int)i00 | (dx1 << 16) | (dy1 << 17);
        uint2 wp;
        wp.x = (unsigned int)bf16bits(w00) | ((unsigned int)bf16bits(w01) << 16);
        wp.y = (unsigned int)bf16bits(w10) | ((unsigned int)bf16bits(w11) << 16);
        wPk[r] = wp;
    }
    __syncthreads();

    floatx4 acc[2][4];
#pragma unroll
    for (int i = 0; i < 2; i++)
#pragma unroll
        for (int j = 0; j < 4; j++) acc[i][j] = (floatx4){0.f, 0.f, 0.f, 0.f};

    unsigned int ipNext; uint2 wpNext;   // params for the NEXT gather iteration

    // ---- stage gk = 0 (and preload parm(1)) ----
    {
        unsigned int ip = iPk[mypix];
        uint2 wp = wPk[mypix];
        int i00 = ip & 0xffff;
        int dx1 = (ip >> 16) & 1, dy1 = (ip >> 17) & 1;
        int i01 = i00 + dx1, i10 = i00 + dy1 * WW, i11 = i10 + dx1;
        const unsigned short* xg = xtb + chunk * 8;     // g = 0
        bf16x8 c00 = *(const bf16x8*)(xg + (size_t)i00 * CIN);
        bf16x8 c01 = *(const bf16x8*)(xg + (size_t)i01 * CIN);
        bf16x8 c10 = *(const bf16x8*)(xg + (size_t)i10 * CIN);
        bf16x8 c11 = *(const bf16x8*)(xg + (size_t)i11 * CIN);
        ipNext = iPk[64 + mypix];
        wpNext = wPk[64 + mypix];
        float w00 = lo_bf(wp.x), w01 = hi_bf(wp.x);
        float w10 = lo_bf(wp.y), w11 = hi_bf(wp.y);
        union { unsigned short u[8]; float4 f; } pk;
#pragma unroll
        for (int i = 0; i < 8; i++) {
            float v = w00 * (float)c00[i] + w01 * (float)c01[i]
                    + w10 * (float)c10[i] + w11 * (float)c11[i];
            pk.u[i] = bf16bits(v);
        }
        *(float4*)&vbuf[0][mypix][swz_w8] = pk.f;
    }
    __syncthreads();

    for (int gk = 0; gk < 36; gk++) {
        int cur = gk & 1;
        bool have = (gk < 35);

        // --- gather gk+1 using pre-loaded params (addresses register-ready) ---
        float nw00, nw01, nw10, nw11;
        bf16x8 n00, n01, n10, n11;
        if (have) {
            unsigned int ip = ipNext; uint2 wp = wpNext;
            int i00 = ip & 0xffff;
            int dx1 = (ip >> 16) & 1, dy1 = (ip >> 17) & 1;
            int i01 = i00 + dx1, i10 = i00 + dy1 * WW, i11 = i10 + dx1;
            const unsigned short* xg = xtb + ((gk + 1) / 9) * 64 + chunk * 8;
            n00 = *(const bf16x8*)(xg + (size_t)i00 * CIN);
            n01 = *(const bf16x8*)(xg + (size_t)i01 * CIN);
            n10 = *(const bf16x8*)(xg + (size_t)i10 * CIN);
            n11 = *(const bf16x8*)(xg + (size_t)i11 * CIN);
            nw00 = lo_bf(wp.x); nw01 = hi_bf(wp.x);
            nw10 = lo_bf(wp.y); nw11 = hi_bf(wp.y);
        }
        // --- preload params for gk+2 (decoupled from next iter's gather) ---
        if (gk < 34) {
            ipNext = iPk[(gk + 2) * 64 + mypix];
            wpNext = wPk[(gk + 2) * 64 + mypix];
        }

        // --- MFMA phase (gk) ---
        const unsigned short* wb = wt2 + gk * 64 + quad * 8;
        __builtin_amdgcn_s_setprio(1);
#pragma unroll
        for (int ks = 0; ks < 2; ks++) {
            int u8 = ((ks * 4 + quad) * 8) ^ m7;
            bf16x8 bf0 = *(const bf16x8*)&vbuf[cur][n16     ][u8];
            bf16x8 bf1 = *(const bf16x8*)&vbuf[cur][16 + n16][u8];
            bf16x8 bf2 = *(const bf16x8*)&vbuf[cur][32 + n16][u8];
            bf16x8 bf3 = *(const bf16x8*)&vbuf[cur][48 + n16][u8];
#pragma unroll
            for (int oi = 0; oi < 2; oi++) {
                bf16x8 a = *(const bf16x8*)&wb[(size_t)(ocbase + oi * 16 + n16) * 2304 + ks * 32];
                acc[oi][0] = __builtin_amdgcn_mfma_f32_16x16x32_bf16(a, bf0, acc[oi][0], 0, 0, 0);
                acc[oi][1] = __builtin_amdgcn_mfma_f32_16x16x32_bf16(a, bf1, acc[oi][1], 0, 0, 0);
                acc[oi][2] = __builtin_amdgcn_mfma_f32_16x16x32_bf16(a, bf2, acc[oi][2], 0, 0, 0);
                acc[oi][3] = __builtin_amdgcn_mfma_f32_16x16x32_bf16(a, bf3, acc[oi][3], 0, 0, 0);
            }
        }
        __builtin_amdgcn_s_setprio(0);

        if (have) {
            union { unsigned short u[8]; float4 f; } pk;
#pragma unroll
            for (int i = 0; i < 8; i++) {
                float v = nw00 * (float)n00[i] + nw01 * (float)n01[i]
                        + nw10 * (float)n10[i] + nw11 * (float)n11[i];
                pk.u[i] = bf16bits(v);
            }
            *(float4*)&vbuf[cur ^ 1][mypix][swz_w8] = pk.f;
            __syncthreads();
        }
    }

    // ---- epilogue: ReLU + store ----
#pragma unroll
    for (int oi = 0; oi < 2; oi++)
#pragma unroll
        for (int pt = 0; pt < 4; pt++) {
            int gpix = pix0 + pt * 16 + n16;
#pragma unroll
            for (int r = 0; r < 4; r++) {
                int oc = ocbase + oi * 16 + quad * 4 + r;
                out[((size_t)(b * OCH + oc)) * NPIX + gpix] = fmaxf(acc[oi][pt][r], 0.f);
            }
        }
}

// ---------------------------------------------------------------------------
extern "C" void kernel_launch(void* const* d_in, const int* in_sizes, int n_in,
                              void* d_out, int out_size, void* d_ws, size_t ws_size,
                              hipStream_t stream) {
    const float* x     = (const float*)d_in[0];
    const float* w_om  = (const float*)d_in[1];
    const float* b_om  = (const float*)d_in[2];
    const float* w_dcn = (const float*)d_in[3];
    float* out = (float*)d_out;

    // workspace layout (77.3 MB total)
    char* ws = (char*)d_ws;
    float*          om   = (float*)(ws);                         // 34,560,000 B
    unsigned short* xT   = (unsigned short*)(ws + 34560000);     // 40,960,000 B
    unsigned short* wom2 = (unsigned short*)(ws + 75520000);     //    589,824 B
    unsigned short* wt2  = (unsigned short*)(ws + 76109824);     //  1,179,648 B

    transpose_x<<<1250, 256, 0, stream>>>(x, xT);
    prep_wom   <<<1152, 256, 0, stream>>>(w_om, wom2);
    prep_wdcn  <<<2304, 256, 0, stream>>>(w_dcn, wt2);
    om_mfma    <<< 625, 512, 0, stream>>>(xT, wom2, b_om, om);
    dcn_mfma   <<<1250, 512, 0, stream>>>(xT, om, wt2, out);
}

// Round 3
// 503.544 us; speedup vs baseline: 2.1871x; 2.1666x over previous
//
#include <hip/hip_runtime.h>
#include <math.h>

// Problem constants
#define HH 200
#define WW 200
#define CIN 256
#define OMCH 108   // 72 offset + 36 mask
#define OCH 256
#define NPIX (HH*WW)

typedef __bf16 bf16x8 __attribute__((ext_vector_type(8)));
typedef float floatx4 __attribute__((ext_vector_type(4)));

static __device__ __forceinline__ unsigned short bf16bits(float v) {
    __bf16 h = (__bf16)v;
    return __builtin_bit_cast(unsigned short, h);
}
static __device__ __forceinline__ float lo_bf(unsigned int u) {
    return __builtin_bit_cast(float, u << 16);
}
static __device__ __forceinline__ float hi_bf(unsigned int u) {
    return __builtin_bit_cast(float, u & 0xffff0000u);
}

// ---------------------------------------------------------------------------
// P0: x [B][C][HW] fp32 -> xT [B][HW][C] bf16.  64-pixel tiles, LDS transpose.
__global__ __launch_bounds__(256) void transpose_x(const float* __restrict__ x,
                                                   unsigned short* __restrict__ xT) {
    __shared__ __align__(16) unsigned short st[64][264];
    int t = threadIdx.x;
    int blk = blockIdx.x;                 // 2 * 625
    int b = blk / 625, pix0 = (blk % 625) * 64;
    const float* xb = x + (size_t)b * CIN * NPIX + pix0;
    int p = t & 63, oct = t >> 6;

    for (int c32 = 0; c32 < CIN; c32 += 32) {
        int c = c32 + oct * 8;
        union { unsigned short u[8]; float4 f; } pk;
#pragma unroll
        for (int i = 0; i < 8; i++)
            pk.u[i] = bf16bits(xb[(size_t)(c + i) * NPIX + p]);
        *(float4*)&st[p][c] = pk.f;
    }
    __syncthreads();
    int p2 = t >> 2, qo = t & 3;
    unsigned short* dst = xT + ((size_t)b * NPIX + pix0 + p2) * CIN + qo * 64;
#pragma unroll
    for (int j = 0; j < 8; j++)
        *(float4*)(dst + j * 8) = *(const float4*)&st[p2][qo * 64 + j * 8];
}

// ---------------------------------------------------------------------------
// P1: w_om [108][256][3][3] fp32 -> wom2 bf16 [128 padded oc][klin], klin = tap*256 + c
__global__ void prep_wom(const float* __restrict__ w, unsigned short* __restrict__ wom2) {
    int i = blockIdx.x * 256 + threadIdx.x;   // i < 128*2304
    int oc = i / 2304, klin = i % 2304;
    int tap = klin >> 8, c = klin & 255;
    float v = (oc < OMCH) ? w[(size_t)oc * 2304 + c * 9 + tap] : 0.f;
    wom2[i] = bf16bits(v);
}

// P2: w_dcn [256][256][3][3] fp32 -> wt2 bf16 [oc][klin], klin = (g*9+k)*64 + c
__global__ void prep_wdcn(const float* __restrict__ w, unsigned short* __restrict__ wt2) {
    int i = blockIdx.x * 256 + threadIdx.x;   // i < 256*2304
    int oc = i / 2304, klin = i % 2304;
    int gk = klin >> 6, c = klin & 63;
    int g = gk / 9, kk = gk % 9;
    wt2[i] = bf16bits(w[(size_t)oc * 2304 + (g * 64 + c) * 9 + kk]);
}

// ---------------------------------------------------------------------------
// K1: om conv via bf16 MFMA. 512 thr / 8 waves, 128 px/block.
// Waves: (wv&3) -> oc quarter, (wv>>2) -> pixel half (64 px each).
// 36 iters: tap (9) x 64-ch chunk (4); stage v[64c][128p] from xT, pipelined.
__global__ __launch_bounds__(512, 6) void om_mfma(const unsigned short* __restrict__ xT,
                                                  const unsigned short* __restrict__ wom2,
                                                  const float* __restrict__ bom,
                                                  float* __restrict__ om) {
    __shared__ __align__(16) unsigned short vbuf[2][128][72];  // [p][64c + 8 pad] = 36864 B

    int t = threadIdx.x;
    int p4 = t >> 2;                      // staging pixel 0..127
    int c4 = t & 3;                       // staging chunk 0..3
    int lane = t & 63, n16 = t & 15, quad = lane >> 4, wv = t >> 6;
    int ocbase = (wv & 3) * 32;
    int ph = (wv >> 2) * 64;

    int gp0 = blockIdx.x * 128;           // 625 blocks over 80000 flat pixels
    int sp = gp0 + p4;                    // staging flat pixel (may straddle batch)
    int sb = (sp >= NPIX) ? 1 : 0;
    int srem = sp - sb * NPIX;
    int sh = srem / WW, sw = srem % WW;
    const unsigned short* xtb = xT + (size_t)sb * NPIX * CIN;

    floatx4 acc[2][4];
#pragma unroll
    for (int i = 0; i < 2; i++)
#pragma unroll
        for (int j = 0; j < 4; j++) acc[i][j] = (floatx4){0.f, 0.f, 0.f, 0.f};

    // stage it=0 (tap 0: di=-1,dj=-1; c0=0)
    {
        int h2 = sh - 1, w2 = sw - 1;
        bool valid = ((unsigned)h2 < (unsigned)HH) && ((unsigned)w2 < (unsigned)WW);
        float4 fa = {0.f,0.f,0.f,0.f}, fb = {0.f,0.f,0.f,0.f};
        if (valid) {
            const unsigned short* src = xtb + (size_t)(h2 * WW + w2) * CIN + c4 * 8;
            fa = *(const float4*)src;
            fb = *(const float4*)(src + 32);
        }
        *(float4*)&vbuf[0][p4][c4 * 8]      = fa;
        *(float4*)&vbuf[0][p4][32 + c4 * 8] = fb;
    }
    __syncthreads();

    for (int it = 0; it < 36; it++) {
        int tap = it >> 2, c0 = (it & 3) << 6;
        int cur = it & 1;
        bool have = (it < 35);

        // --- prefetch next staging chunk into registers ---
        float4 nfa = {0.f,0.f,0.f,0.f}, nfb = {0.f,0.f,0.f,0.f};
        if (have) {
            int itn = it + 1;
            int tapn = itn >> 2, c0n = (itn & 3) << 6;
            int h2 = sh + tapn / 3 - 1, w2 = sw + tapn % 3 - 1;
            bool valid = ((unsigned)h2 < (unsigned)HH) && ((unsigned)w2 < (unsigned)WW);
            if (valid) {
                const unsigned short* src = xtb + (size_t)(h2 * WW + w2) * CIN + c0n + c4 * 8;
                nfa = *(const float4*)src;
                nfb = *(const float4*)(src + 32);
            }
        }

        // --- MFMA phase ---
        const unsigned short* wb = wom2 + (size_t)(tap * 256 + c0) + quad * 8;
#pragma unroll
        for (int ks = 0; ks < 2; ks++) {
            bf16x8 bf0 = *(const bf16x8*)&vbuf[cur][ph + n16     ][ks * 32 + quad * 8];
            bf16x8 bf1 = *(const bf16x8*)&vbuf[cur][ph + 16 + n16][ks * 32 + quad * 8];
            bf16x8 bf2 = *(const bf16x8*)&vbuf[cur][ph + 32 + n16][ks * 32 + quad * 8];
            bf16x8 bf3 = *(const bf16x8*)&vbuf[cur][ph + 48 + n16][ks * 32 + quad * 8];
#pragma unroll
            for (int oi = 0; oi < 2; oi++) {
                bf16x8 a = *(const bf16x8*)&wb[(size_t)(ocbase + oi * 16 + n16) * 2304 + ks * 32];
                acc[oi][0] = __builtin_amdgcn_mfma_f32_16x16x32_bf16(a, bf0, acc[oi][0], 0, 0, 0);
                acc[oi][1] = __builtin_amdgcn_mfma_f32_16x16x32_bf16(a, bf1, acc[oi][1], 0, 0, 0);
                acc[oi][2] = __builtin_amdgcn_mfma_f32_16x16x32_bf16(a, bf2, acc[oi][2], 0, 0, 0);
                acc[oi][3] = __builtin_amdgcn_mfma_f32_16x16x32_bf16(a, bf3, acc[oi][3], 0, 0, 0);
            }
        }

        if (have) {
            *(float4*)&vbuf[cur ^ 1][p4][c4 * 8]      = nfa;
            *(float4*)&vbuf[cur ^ 1][p4][32 + c4 * 8] = nfb;
            __syncthreads();
        }
    }

    // epilogue: D col = n16 (pixel), row = quad*4+r (oc); + bias
#pragma unroll
    for (int oi = 0; oi < 2; oi++) {
        int oc0 = ocbase + oi * 16 + quad * 4;
        if (oc0 < OMCH) {
#pragma unroll
            for (int pt = 0; pt < 4; pt++) {
                int fp = gp0 + ph + pt * 16 + n16;
                int bq = (fp >= NPIX) ? 1 : 0;
                int rem = fp - bq * NPIX;
#pragma unroll
                for (int r = 0; r < 4; r++) {
                    int occ = oc0 + r;
                    if (occ < OMCH)
                        om[((size_t)(bq * OMCH + occ)) * NPIX + rem] = acc[oi][pt][r] + bom[occ];
                }
            }
        }
    }
}

// ---------------------------------------------------------------------------
// K2: fused DCN. 512 thr / 8 waves, 64 px/block. Wave wv -> oc [32wv, +32).
// Params packed to 12 B/record in LDS (46 KB total -> 3 blocks/CU).
// Pipeline: parm(gk+2) LDS-read || gather(gk+1) || MFMA(gk) || pack(gk+1).
__global__ __launch_bounds__(512, 6) void dcn_mfma(const unsigned short* __restrict__ xT,
                                                   const float* __restrict__ om,
                                                   const unsigned short* __restrict__ wt2,
                                                   float* __restrict__ out) {
    __shared__ unsigned int iPk[36 * 64];                    //  9216 B: i00 | dx1<<16 | dy1<<17
    __shared__ uint2        wPk[36 * 64];                    // 18432 B: 4 x bf16 corner weights
    __shared__ __align__(16) unsigned short vbuf[2][64][72]; // 18432 B

    int t = threadIdx.x;
    int l = t & 63;
    int oct = t >> 6;             // wave id
    int p8 = l >> 3;              // pixel sub-index within wave
    int chunk = l & 7;            // 16B channel chunk
    int mypix = oct * 8 + p8;     // staging pixel 0..63
    int n16 = t & 15, quad = l >> 4;
    int ocbase = oct * 32;

    int gp0 = blockIdx.x * 64;    // 1250 blocks; 40000 % 64 == 0, no batch straddle
    int b = gp0 / NPIX;
    int pix0 = gp0 - b * NPIX;
    const unsigned short* xtb = xT + (size_t)b * NPIX * CIN;
    const float* omb = om + (size_t)b * OMCH * NPIX;

    // ---- prologue: packed sampling params for all (gk, p) ----
    for (int r = t; r < 36 * 64; r += 512) {
        int gk = r >> 6, p = r & 63;
        int g = gk / 9, kk = gk % 9;
        int ki = kk / 3, kj = kk % 3;
        int pp = pix0 + p;
        int hh = pp / WW, ww2 = pp % WW;
        float dy = omb[(size_t)(g * 18 + 2 * kk    ) * NPIX + pp];
        float dx = omb[(size_t)(g * 18 + 2 * kk + 1) * NPIX + pp];
        float mr = omb[(size_t)(72 + g * 9 + kk    ) * NPIX + pp];
        float m = 1.f / (1.f + __expf(-mr));
        float py = (float)(hh - 1 + ki) + dy;
        float px = (float)(ww2 - 1 + kj) + dx;
        float fy = floorf(py), fx = floorf(px);
        float wy = py - fy, wx = px - fx;
        int y0 = (int)fy, x0 = (int)fx, y1 = y0 + 1, x1 = x0 + 1;
        bool vy0 = (y0 >= 0) && (y0 < HH), vy1 = (y1 >= 0) && (y1 < HH);
        bool vx0 = (x0 >= 0) && (x0 < WW), vx1 = (x1 >= 0) && (x1 < WW);
        int cy0 = min(max(y0, 0), HH - 1), cy1 = min(max(y1, 0), HH - 1);
        int cx0 = min(max(x0, 0), WW - 1), cx1 = min(max(x1, 0), WW - 1);
        float w00 = (vy0 && vx0) ? (1.f - wy) * (1.f - wx) * m : 0.f;
        float w01 = (vy0 && vx1) ? (1.f - wy) * wx * m : 0.f;
        float w10 = (vy1 && vx0) ? wy * (1.f - wx) * m : 0.f;
        float w11 = (vy1 && vx1) ? wy * wx * m : 0.f;
        int i00 = cy0 * WW + cx0;
        unsigned int dx1 = (unsigned int)(cx1 - cx0);   // 0/1
        unsigned int dy1 = (unsigned int)(cy1 - cy0);   // 0/1
        iPk[r] = (unsigned int)i00 | (dx1 << 16) | (dy1 << 17);
        uint2 wp;
        wp.x = (unsigned int)bf16bits(w00) | ((unsigned int)bf16bits(w01) << 16);
        wp.y = (unsigned int)bf16bits(w10) | ((unsigned int)bf16bits(w11) << 16);
        wPk[r] = wp;
    }
    __syncthreads();

    floatx4 acc[2][4];
#pragma unroll
    for (int i = 0; i < 2; i++)
#pragma unroll
        for (int j = 0; j < 4; j++) acc[i][j] = (floatx4){0.f, 0.f, 0.f, 0.f};

    unsigned int ipNext; uint2 wpNext;   // params for the NEXT gather iteration

    // ---- stage gk = 0 (and preload parm(1)) ----
    {
        unsigned int ip = iPk[mypix];
        uint2 wp = wPk[mypix];
        int i00 = ip & 0xffff;
        int dx1 = (ip >> 16) & 1, dy1 = (ip >> 17) & 1;
        int i01 = i00 + dx1, i10 = i00 + dy1 * WW, i11 = i10 + dx1;
        const unsigned short* xg = xtb + chunk * 8;     // g = 0
        bf16x8 c00 = *(const bf16x8*)(xg + (size_t)i00 * CIN);
        bf16x8 c01 = *(const bf16x8*)(xg + (size_t)i01 * CIN);
        bf16x8 c10 = *(const bf16x8*)(xg + (size_t)i10 * CIN);
        bf16x8 c11 = *(const bf16x8*)(xg + (size_t)i11 * CIN);
        ipNext = iPk[64 + mypix];
        wpNext = wPk[64 + mypix];
        float w00 = lo_bf(wp.x), w01 = hi_bf(wp.x);
        float w10 = lo_bf(wp.y), w11 = hi_bf(wp.y);
        union { unsigned short u[8]; float4 f; } pk;
#pragma unroll
        for (int i = 0; i < 8; i++) {
            float v = w00 * (float)c00[i] + w01 * (float)c01[i]
                    + w10 * (float)c10[i] + w11 * (float)c11[i];
            pk.u[i] = bf16bits(v);
        }
        *(float4*)&vbuf[0][mypix][chunk * 8] = pk.f;
    }
    __syncthreads();

    for (int gk = 0; gk < 36; gk++) {
        int cur = gk & 1;
        bool have = (gk < 35);

        // --- gather gk+1 using pre-loaded params (addresses register-ready) ---
        float nw00, nw01, nw10, nw11;
        bf16x8 n00, n01, n10, n11;
        if (have) {
            unsigned int ip = ipNext; uint2 wp = wpNext;
            int i00 = ip & 0xffff;
            int dx1 = (ip >> 16) & 1, dy1 = (ip >> 17) & 1;
            int i01 = i00 + dx1, i10 = i00 + dy1 * WW, i11 = i10 + dx1;
            const unsigned short* xg = xtb + ((gk + 1) / 9) * 64 + chunk * 8;
            n00 = *(const bf16x8*)(xg + (size_t)i00 * CIN);
            n01 = *(const bf16x8*)(xg + (size_t)i01 * CIN);
            n10 = *(const bf16x8*)(xg + (size_t)i10 * CIN);
            n11 = *(const bf16x8*)(xg + (size_t)i11 * CIN);
            nw00 = lo_bf(wp.x); nw01 = hi_bf(wp.x);
            nw10 = lo_bf(wp.y); nw11 = hi_bf(wp.y);
        }
        // --- preload params for gk+2 (decoupled from next iter's gather) ---
        if (gk < 34) {
            ipNext = iPk[(gk + 2) * 64 + mypix];
            wpNext = wPk[(gk + 2) * 64 + mypix];
        }

        // --- MFMA phase (gk) ---
        const unsigned short* wb = wt2 + gk * 64 + quad * 8;
#pragma unroll
        for (int ks = 0; ks < 2; ks++) {
            bf16x8 bf0 = *(const bf16x8*)&vbuf[cur][n16     ][ks * 32 + quad * 8];
            bf16x8 bf1 = *(const bf16x8*)&vbuf[cur][16 + n16][ks * 32 + quad * 8];
            bf16x8 bf2 = *(const bf16x8*)&vbuf[cur][32 + n16][ks * 32 + quad * 8];
            bf16x8 bf3 = *(const bf16x8*)&vbuf[cur][48 + n16][ks * 32 + quad * 8];
#pragma unroll
            for (int oi = 0; oi < 2; oi++) {
                bf16x8 a = *(const bf16x8*)&wb[(size_t)(ocbase + oi * 16 + n16) * 2304 + ks * 32];
                acc[oi][0] = __builtin_amdgcn_mfma_f32_16x16x32_bf16(a, bf0, acc[oi][0], 0, 0, 0);
                acc[oi][1] = __builtin_amdgcn_mfma_f32_16x16x32_bf16(a, bf1, acc[oi][1], 0, 0, 0);
                acc[oi][2] = __builtin_amdgcn_mfma_f32_16x16x32_bf16(a, bf2, acc[oi][2], 0, 0, 0);
                acc[oi][3] = __builtin_amdgcn_mfma_f32_16x16x32_bf16(a, bf3, acc[oi][3], 0, 0, 0);
            }
        }

        if (have) {
            union { unsigned short u[8]; float4 f; } pk;
#pragma unroll
            for (int i = 0; i < 8; i++) {
                float v = nw00 * (float)n00[i] + nw01 * (float)n01[i]
                        + nw10 * (float)n10[i] + nw11 * (float)n11[i];
                pk.u[i] = bf16bits(v);
            }
            *(float4*)&vbuf[cur ^ 1][mypix][chunk * 8] = pk.f;
            __syncthreads();
        }
    }

    // ---- epilogue: ReLU + store ----
#pragma unroll
    for (int oi = 0; oi < 2; oi++)
#pragma unroll
        for (int pt = 0; pt < 4; pt++) {
            int gpix = pix0 + pt * 16 + n16;
#pragma unroll
            for (int r = 0; r < 4; r++) {
                int oc = ocbase + oi * 16 + quad * 4 + r;
                out[((size_t)(b * OCH + oc)) * NPIX + gpix] = fmaxf(acc[oi][pt][r], 0.f);
            }
        }
}

// ---------------------------------------------------------------------------
extern "C" void kernel_launch(void* const* d_in, const int* in_sizes, int n_in,
                              void* d_out, int out_size, void* d_ws, size_t ws_size,
                              hipStream_t stream) {
    const float* x     = (const float*)d_in[0];
    const float* w_om  = (const float*)d_in[1];
    const float* b_om  = (const float*)d_in[2];
    const float* w_dcn = (const float*)d_in[3];
    float* out = (float*)d_out;

    // workspace layout (77.3 MB total)
    char* ws = (char*)d_ws;
    float*          om   = (float*)(ws);                         // 34,560,000 B
    unsigned short* xT   = (unsigned short*)(ws + 34560000);     // 40,960,000 B
    unsigned short* wom2 = (unsigned short*)(ws + 75520000);     //    589,824 B
    unsigned short* wt2  = (unsigned short*)(ws + 76109824);     //  1,179,648 B

    transpose_x<<<1250, 256, 0, stream>>>(x, xT);
    prep_wom   <<<1152, 256, 0, stream>>>(w_om, wom2);
    prep_wdcn  <<<2304, 256, 0, stream>>>(w_dcn, wt2);
    om_mfma    <<< 625, 512, 0, stream>>>(xT, wom2, b_om, om);
    dcn_mfma   <<<1250, 512, 0, stream>>>(xT, om, wt2, out);
}

// Round 4
// 498.550 us; speedup vs baseline: 2.2091x; 1.0100x over previous
//
#include <hip/hip_runtime.h>
#include <math.h>

// Problem constants
#define HH 200
#define WW 200
#define CIN 256
#define OMCH 108   // 72 offset + 36 mask
#define OCH 256
#define NPIX (HH*WW)

typedef __bf16 bf16x8 __attribute__((ext_vector_type(8)));
typedef float floatx4 __attribute__((ext_vector_type(4)));

static __device__ __forceinline__ unsigned short bf16bits(float v) {
    __bf16 h = (__bf16)v;
    return __builtin_bit_cast(unsigned short, h);
}
static __device__ __forceinline__ float lo_bf(unsigned int u) {
    return __builtin_bit_cast(float, u << 16);
}
static __device__ __forceinline__ float hi_bf(unsigned int u) {
    return __builtin_bit_cast(float, u & 0xffff0000u);
}

// Bijective XCD-chunked swizzle (m204): HW assigns block b -> XCD b%8 round-robin.
// Remap so each XCD processes a CONTIGUOUS chunk of work ids -> xT row neighborhoods
// stay resident in that XCD's private L2 instead of being fetched by all 8.
static __device__ __forceinline__ int xcd_swizzle(int orig, int nwg) {
    int q = nwg >> 3, r = nwg & 7;
    int x = orig & 7, rank = orig >> 3;
    int base = (x < r) ? x * (q + 1) : r * (q + 1) + (x - r) * q;
    return base + rank;
}

// ---------------------------------------------------------------------------
// P0: x [B][C][HW] fp32 -> xT [B][HW][C] bf16.  64-pixel tiles, LDS transpose.
__global__ __launch_bounds__(256) void transpose_x(const float* __restrict__ x,
                                                   unsigned short* __restrict__ xT) {
    __shared__ __align__(16) unsigned short st[64][264];
    int t = threadIdx.x;
    int blk = blockIdx.x;                 // 2 * 625
    int b = blk / 625, pix0 = (blk % 625) * 64;
    const float* xb = x + (size_t)b * CIN * NPIX + pix0;
    int p = t & 63, oct = t >> 6;

    for (int c32 = 0; c32 < CIN; c32 += 32) {
        int c = c32 + oct * 8;
        union { unsigned short u[8]; float4 f; } pk;
#pragma unroll
        for (int i = 0; i < 8; i++)
            pk.u[i] = bf16bits(xb[(size_t)(c + i) * NPIX + p]);
        *(float4*)&st[p][c] = pk.f;
    }
    __syncthreads();
    int p2 = t >> 2, qo = t & 3;
    unsigned short* dst = xT + ((size_t)b * NPIX + pix0 + p2) * CIN + qo * 64;
#pragma unroll
    for (int j = 0; j < 8; j++)
        *(float4*)(dst + j * 8) = *(const float4*)&st[p2][qo * 64 + j * 8];
}

// ---------------------------------------------------------------------------
// P1: w_om [108][256][3][3] fp32 -> wom2 bf16 [128 padded oc][klin], klin = tap*256 + c
__global__ void prep_wom(const float* __restrict__ w, unsigned short* __restrict__ wom2) {
    int i = blockIdx.x * 256 + threadIdx.x;   // i < 128*2304
    int oc = i / 2304, klin = i % 2304;
    int tap = klin >> 8, c = klin & 255;
    float v = (oc < OMCH) ? w[(size_t)oc * 2304 + c * 9 + tap] : 0.f;
    wom2[i] = bf16bits(v);
}

// P2: w_dcn [256][256][3][3] fp32 -> wt2 bf16 [oc][klin], klin = (g*9+k)*64 + c
__global__ void prep_wdcn(const float* __restrict__ w, unsigned short* __restrict__ wt2) {
    int i = blockIdx.x * 256 + threadIdx.x;   // i < 256*2304
    int oc = i / 2304, klin = i % 2304;
    int gk = klin >> 6, c = klin & 63;
    int g = gk / 9, kk = gk % 9;
    wt2[i] = bf16bits(w[(size_t)oc * 2304 + (g * 64 + c) * 9 + kk]);
}

// ---------------------------------------------------------------------------
// K1: om conv via bf16 MFMA. 512 thr / 8 waves, 128 px/block.
// Waves: (wv&3) -> oc quarter, (wv>>2) -> pixel half (64 px each).
// 36 iters: tap (9) x 64-ch chunk (4); stage v[64c][128p] from xT, pipelined.
// XCD-chunked block swizzle for xT L2 locality.
__global__ __launch_bounds__(512, 6) void om_mfma(const unsigned short* __restrict__ xT,
                                                  const unsigned short* __restrict__ wom2,
                                                  const float* __restrict__ bom,
                                                  float* __restrict__ om) {
    __shared__ __align__(16) unsigned short vbuf[2][128][72];  // [p][64c + 8 pad] = 36864 B

    int t = threadIdx.x;
    int p4 = t >> 2;                      // staging pixel 0..127
    int c4 = t & 3;                       // staging chunk 0..3
    int lane = t & 63, n16 = t & 15, quad = lane >> 4, wv = t >> 6;
    int ocbase = (wv & 3) * 32;
    int ph = (wv >> 2) * 64;

    int gp0 = xcd_swizzle(blockIdx.x, 625) * 128;  // 625 blocks over 80000 flat pixels
    int sp = gp0 + p4;                    // staging flat pixel (may straddle batch)
    int sb = (sp >= NPIX) ? 1 : 0;
    int srem = sp - sb * NPIX;
    int sh = srem / WW, sw = srem % WW;
    const unsigned short* xtb = xT + (size_t)sb * NPIX * CIN;

    floatx4 acc[2][4];
#pragma unroll
    for (int i = 0; i < 2; i++)
#pragma unroll
        for (int j = 0; j < 4; j++) acc[i][j] = (floatx4){0.f, 0.f, 0.f, 0.f};

    // stage it=0 (tap 0: di=-1,dj=-1; c0=0)
    {
        int h2 = sh - 1, w2 = sw - 1;
        bool valid = ((unsigned)h2 < (unsigned)HH) && ((unsigned)w2 < (unsigned)WW);
        float4 fa = {0.f,0.f,0.f,0.f}, fb = {0.f,0.f,0.f,0.f};
        if (valid) {
            const unsigned short* src = xtb + (size_t)(h2 * WW + w2) * CIN + c4 * 8;
            fa = *(const float4*)src;
            fb = *(const float4*)(src + 32);
        }
        *(float4*)&vbuf[0][p4][c4 * 8]      = fa;
        *(float4*)&vbuf[0][p4][32 + c4 * 8] = fb;
    }
    __syncthreads();

    for (int it = 0; it < 36; it++) {
        int tap = it >> 2, c0 = (it & 3) << 6;
        int cur = it & 1;
        bool have = (it < 35);

        // --- prefetch next staging chunk into registers ---
        float4 nfa = {0.f,0.f,0.f,0.f}, nfb = {0.f,0.f,0.f,0.f};
        if (have) {
            int itn = it + 1;
            int tapn = itn >> 2, c0n = (itn & 3) << 6;
            int h2 = sh + tapn / 3 - 1, w2 = sw + tapn % 3 - 1;
            bool valid = ((unsigned)h2 < (unsigned)HH) && ((unsigned)w2 < (unsigned)WW);
            if (valid) {
                const unsigned short* src = xtb + (size_t)(h2 * WW + w2) * CIN + c0n + c4 * 8;
                nfa = *(const float4*)src;
                nfb = *(const float4*)(src + 32);
            }
        }

        // --- MFMA phase ---
        const unsigned short* wb = wom2 + (size_t)(tap * 256 + c0) + quad * 8;
#pragma unroll
        for (int ks = 0; ks < 2; ks++) {
            bf16x8 bf0 = *(const bf16x8*)&vbuf[cur][ph + n16     ][ks * 32 + quad * 8];
            bf16x8 bf1 = *(const bf16x8*)&vbuf[cur][ph + 16 + n16][ks * 32 + quad * 8];
            bf16x8 bf2 = *(const bf16x8*)&vbuf[cur][ph + 32 + n16][ks * 32 + quad * 8];
            bf16x8 bf3 = *(const bf16x8*)&vbuf[cur][ph + 48 + n16][ks * 32 + quad * 8];
#pragma unroll
            for (int oi = 0; oi < 2; oi++) {
                bf16x8 a = *(const bf16x8*)&wb[(size_t)(ocbase + oi * 16 + n16) * 2304 + ks * 32];
                acc[oi][0] = __builtin_amdgcn_mfma_f32_16x16x32_bf16(a, bf0, acc[oi][0], 0, 0, 0);
                acc[oi][1] = __builtin_amdgcn_mfma_f32_16x16x32_bf16(a, bf1, acc[oi][1], 0, 0, 0);
                acc[oi][2] = __builtin_amdgcn_mfma_f32_16x16x32_bf16(a, bf2, acc[oi][2], 0, 0, 0);
                acc[oi][3] = __builtin_amdgcn_mfma_f32_16x16x32_bf16(a, bf3, acc[oi][3], 0, 0, 0);
            }
        }

        if (have) {
            *(float4*)&vbuf[cur ^ 1][p4][c4 * 8]      = nfa;
            *(float4*)&vbuf[cur ^ 1][p4][32 + c4 * 8] = nfb;
            __syncthreads();
        }
    }

    // epilogue: D col = n16 (pixel), row = quad*4+r (oc); + bias
#pragma unroll
    for (int oi = 0; oi < 2; oi++) {
        int oc0 = ocbase + oi * 16 + quad * 4;
        if (oc0 < OMCH) {
#pragma unroll
            for (int pt = 0; pt < 4; pt++) {
                int fp = gp0 + ph + pt * 16 + n16;
                int bq = (fp >= NPIX) ? 1 : 0;
                int rem = fp - bq * NPIX;
#pragma unroll
                for (int r = 0; r < 4; r++) {
                    int occ = oc0 + r;
                    if (occ < OMCH)
                        om[((size_t)(bq * OMCH + occ)) * NPIX + rem] = acc[oi][pt][r] + bom[occ];
                }
            }
        }
    }
}

// ---------------------------------------------------------------------------
// K2: fused DCN. 512 thr / 8 waves, 64 px/block. Wave wv -> oc [32wv, +32).
// Params packed to 12 B/record in LDS (46 KB total -> 3 blocks/CU).
// Pipeline: parm(gk+2) LDS-read || gather(gk+1) || MFMA(gk) || pack(gk+1).
// XCD-chunked block swizzle for xT gather L2 locality.
__global__ __launch_bounds__(512, 6) void dcn_mfma(const unsigned short* __restrict__ xT,
                                                   const float* __restrict__ om,
                                                   const unsigned short* __restrict__ wt2,
                                                   float* __restrict__ out) {
    __shared__ unsigned int iPk[36 * 64];                    //  9216 B: i00 | dx1<<16 | dy1<<17
    __shared__ uint2        wPk[36 * 64];                    // 18432 B: 4 x bf16 corner weights
    __shared__ __align__(16) unsigned short vbuf[2][64][72]; // 18432 B

    int t = threadIdx.x;
    int l = t & 63;
    int oct = t >> 6;             // wave id
    int p8 = l >> 3;              // pixel sub-index within wave
    int chunk = l & 7;            // 16B channel chunk
    int mypix = oct * 8 + p8;     // staging pixel 0..63
    int n16 = t & 15, quad = l >> 4;
    int ocbase = oct * 32;

    int gp0 = xcd_swizzle(blockIdx.x, 1250) * 64;  // 1250 blocks; 40000 % 64 == 0
    int b = gp0 / NPIX;
    int pix0 = gp0 - b * NPIX;
    const unsigned short* xtb = xT + (size_t)b * NPIX * CIN;
    const float* omb = om + (size_t)b * OMCH * NPIX;

    // ---- prologue: packed sampling params for all (gk, p) ----
    for (int r = t; r < 36 * 64; r += 512) {
        int gk = r >> 6, p = r & 63;
        int g = gk / 9, kk = gk % 9;
        int ki = kk / 3, kj = kk % 3;
        int pp = pix0 + p;
        int hh = pp / WW, ww2 = pp % WW;
        float dy = omb[(size_t)(g * 18 + 2 * kk    ) * NPIX + pp];
        float dx = omb[(size_t)(g * 18 + 2 * kk + 1) * NPIX + pp];
        float mr = omb[(size_t)(72 + g * 9 + kk    ) * NPIX + pp];
        float m = 1.f / (1.f + __expf(-mr));
        float py = (float)(hh - 1 + ki) + dy;
        float px = (float)(ww2 - 1 + kj) + dx;
        float fy = floorf(py), fx = floorf(px);
        float wy = py - fy, wx = px - fx;
        int y0 = (int)fy, x0 = (int)fx, y1 = y0 + 1, x1 = x0 + 1;
        bool vy0 = (y0 >= 0) && (y0 < HH), vy1 = (y1 >= 0) && (y1 < HH);
        bool vx0 = (x0 >= 0) && (x0 < WW), vx1 = (x1 >= 0) && (x1 < WW);
        int cy0 = min(max(y0, 0), HH - 1), cy1 = min(max(y1, 0), HH - 1);
        int cx0 = min(max(x0, 0), WW - 1), cx1 = min(max(x1, 0), WW - 1);
        float w00 = (vy0 && vx0) ? (1.f - wy) * (1.f - wx) * m : 0.f;
        float w01 = (vy0 && vx1) ? (1.f - wy) * wx * m : 0.f;
        float w10 = (vy1 && vx0) ? wy * (1.f - wx) * m : 0.f;
        float w11 = (vy1 && vx1) ? wy * wx * m : 0.f;
        int i00 = cy0 * WW + cx0;
        unsigned int dx1 = (unsigned int)(cx1 - cx0);   // 0/1
        unsigned int dy1 = (unsigned int)(cy1 - cy0);   // 0/1
        iPk[r] = (unsigned int)i00 | (dx1 << 16) | (dy1 << 17);
        uint2 wp;
        wp.x = (unsigned int)bf16bits(w00) | ((unsigned int)bf16bits(w01) << 16);
        wp.y = (unsigned int)bf16bits(w10) | ((unsigned int)bf16bits(w11) << 16);
        wPk[r] = wp;
    }
    __syncthreads();

    floatx4 acc[2][4];
#pragma unroll
    for (int i = 0; i < 2; i++)
#pragma unroll
        for (int j = 0; j < 4; j++) acc[i][j] = (floatx4){0.f, 0.f, 0.f, 0.f};

    unsigned int ipNext; uint2 wpNext;   // params for the NEXT gather iteration

    // ---- stage gk = 0 (and preload parm(1)) ----
    {
        unsigned int ip = iPk[mypix];
        uint2 wp = wPk[mypix];
        int i00 = ip & 0xffff;
        int dx1 = (ip >> 16) & 1, dy1 = (ip >> 17) & 1;
        int i01 = i00 + dx1, i10 = i00 + dy1 * WW, i11 = i10 + dx1;
        const unsigned short* xg = xtb + chunk * 8;     // g = 0
        bf16x8 c00 = *(const bf16x8*)(xg + (size_t)i00 * CIN);
        bf16x8 c01 = *(const bf16x8*)(xg + (size_t)i01 * CIN);
        bf16x8 c10 = *(const bf16x8*)(xg + (size_t)i10 * CIN);
        bf16x8 c11 = *(const bf16x8*)(xg + (size_t)i11 * CIN);
        ipNext = iPk[64 + mypix];
        wpNext = wPk[64 + mypix];
        float w00 = lo_bf(wp.x), w01 = hi_bf(wp.x);
        float w10 = lo_bf(wp.y), w11 = hi_bf(wp.y);
        union { unsigned short u[8]; float4 f; } pk;
#pragma unroll
        for (int i = 0; i < 8; i++) {
            float v = w00 * (float)c00[i] + w01 * (float)c01[i]
                    + w10 * (float)c10[i] + w11 * (float)c11[i];
            pk.u[i] = bf16bits(v);
        }
        *(float4*)&vbuf[0][mypix][chunk * 8] = pk.f;
    }
    __syncthreads();

    for (int gk = 0; gk < 36; gk++) {
        int cur = gk & 1;
        bool have = (gk < 35);

        // --- gather gk+1 using pre-loaded params (addresses register-ready) ---
        float nw00, nw01, nw10, nw11;
        bf16x8 n00, n01, n10, n11;
        if (have) {
            unsigned int ip = ipNext; uint2 wp = wpNext;
            int i00 = ip & 0xffff;
            int dx1 = (ip >> 16) & 1, dy1 = (ip >> 17) & 1;
            int i01 = i00 + dx1, i10 = i00 + dy1 * WW, i11 = i10 + dx1;
            const unsigned short* xg = xtb + ((gk + 1) / 9) * 64 + chunk * 8;
            n00 = *(const bf16x8*)(xg + (size_t)i00 * CIN);
            n01 = *(const bf16x8*)(xg + (size_t)i01 * CIN);
            n10 = *(const bf16x8*)(xg + (size_t)i10 * CIN);
            n11 = *(const bf16x8*)(xg + (size_t)i11 * CIN);
            nw00 = lo_bf(wp.x); nw01 = hi_bf(wp.x);
            nw10 = lo_bf(wp.y); nw11 = hi_bf(wp.y);
        }
        // --- preload params for gk+2 (decoupled from next iter's gather) ---
        if (gk < 34) {
            ipNext = iPk[(gk + 2) * 64 + mypix];
            wpNext = wPk[(gk + 2) * 64 + mypix];
        }

        // --- MFMA phase (gk) ---
        const unsigned short* wb = wt2 + gk * 64 + quad * 8;
#pragma unroll
        for (int ks = 0; ks < 2; ks++) {
            bf16x8 bf0 = *(const bf16x8*)&vbuf[cur][n16     ][ks * 32 + quad * 8];
            bf16x8 bf1 = *(const bf16x8*)&vbuf[cur][16 + n16][ks * 32 + quad * 8];
            bf16x8 bf2 = *(const bf16x8*)&vbuf[cur][32 + n16][ks * 32 + quad * 8];
            bf16x8 bf3 = *(const bf16x8*)&vbuf[cur][48 + n16][ks * 32 + quad * 8];
#pragma unroll
            for (int oi = 0; oi < 2; oi++) {
                bf16x8 a = *(const bf16x8*)&wb[(size_t)(ocbase + oi * 16 + n16) * 2304 + ks * 32];
                acc[oi][0] = __builtin_amdgcn_mfma_f32_16x16x32_bf16(a, bf0, acc[oi][0], 0, 0, 0);
                acc[oi][1] = __builtin_amdgcn_mfma_f32_16x16x32_bf16(a, bf1, acc[oi][1], 0, 0, 0);
                acc[oi][2] = __builtin_amdgcn_mfma_f32_16x16x32_bf16(a, bf2, acc[oi][2], 0, 0, 0);
                acc[oi][3] = __builtin_amdgcn_mfma_f32_16x16x32_bf16(a, bf3, acc[oi][3], 0, 0, 0);
            }
        }

        if (have) {
            union { unsigned short u[8]; float4 f; } pk;
#pragma unroll
            for (int i = 0; i < 8; i++) {
                float v = nw00 * (float)n00[i] + nw01 * (float)n01[i]
                        + nw10 * (float)n10[i] + nw11 * (float)n11[i];
                pk.u[i] = bf16bits(v);
            }
            *(float4*)&vbuf[cur ^ 1][mypix][chunk * 8] = pk.f;
            __syncthreads();
        }
    }

    // ---- epilogue: ReLU + store ----
#pragma unroll
    for (int oi = 0; oi < 2; oi++)
#pragma unroll
        for (int pt = 0; pt < 4; pt++) {
            int gpix = pix0 + pt * 16 + n16;
#pragma unroll
            for (int r = 0; r < 4; r++) {
                int oc = ocbase + oi * 16 + quad * 4 + r;
                out[((size_t)(b * OCH + oc)) * NPIX + gpix] = fmaxf(acc[oi][pt][r], 0.f);
            }
        }
}

// ---------------------------------------------------------------------------
extern "C" void kernel_launch(void* const* d_in, const int* in_sizes, int n_in,
                              void* d_out, int out_size, void* d_ws, size_t ws_size,
                              hipStream_t stream) {
    const float* x     = (const float*)d_in[0];
    const float* w_om  = (const float*)d_in[1];
    const float* b_om  = (const float*)d_in[2];
    const float* w_dcn = (const float*)d_in[3];
    float* out = (float*)d_out;

    // workspace layout (77.3 MB total)
    char* ws = (char*)d_ws;
    float*          om   = (float*)(ws);                         // 34,560,000 B
    unsigned short* xT   = (unsigned short*)(ws + 34560000);     // 40,960,000 B
    unsigned short* wom2 = (unsigned short*)(ws + 75520000);     //    589,824 B
    unsigned short* wt2  = (unsigned short*)(ws + 76109824);     //  1,179,648 B

    transpose_x<<<1250, 256, 0, stream>>>(x, xT);
    prep_wom   <<<1152, 256, 0, stream>>>(w_om, wom2);
    prep_wdcn  <<<2304, 256, 0, stream>>>(w_dcn, wt2);
    om_mfma    <<< 625, 512, 0, stream>>>(xT, wom2, b_om, om);
    dcn_mfma   <<<1250, 512, 0, stream>>>(xT, om, wt2, out);
}

// Round 6
// 410.910 us; speedup vs baseline: 2.6802x; 1.2133x over previous
//
#include <hip/hip_runtime.h>
#include <math.h>

// Problem constants
#define HH 200
#define WW 200
#define CIN 256
#define OMCH 108   // 72 offset + 36 mask
#define OCH 256
#define NPIX (HH*WW)

typedef __bf16 bf16x8 __attribute__((ext_vector_type(8)));
typedef float floatx4 __attribute__((ext_vector_type(4)));

static __device__ __forceinline__ unsigned short bf16bits(float v) {
    __bf16 h = (__bf16)v;
    return __builtin_bit_cast(unsigned short, h);
}
static __device__ __forceinline__ float lo_bf(unsigned int u) {
    return __builtin_bit_cast(float, u << 16);
}
static __device__ __forceinline__ float hi_bf(unsigned int u) {
    return __builtin_bit_cast(float, u & 0xffff0000u);
}

// Bijective XCD-chunked swizzle (m204): HW assigns block b -> XCD b%8 round-robin.
// Remap so each XCD processes a CONTIGUOUS chunk of work ids -> xT row neighborhoods
// stay resident in that XCD's private L2 instead of being fetched by all 8.
static __device__ __forceinline__ int xcd_swizzle(int orig, int nwg) {
    int q = nwg >> 3, r = nwg & 7;
    int x = orig & 7, rank = orig >> 3;
    int base = (x < r) ? x * (q + 1) : r * (q + 1) + (x - r) * q;
    return base + rank;
}

// ---------------------------------------------------------------------------
// P0: x [B][C][HW] fp32 -> xT [B][HW][C] bf16.  64-pixel tiles, LDS transpose.
__global__ __launch_bounds__(256) void transpose_x(const float* __restrict__ x,
                                                   unsigned short* __restrict__ xT) {
    __shared__ __align__(16) unsigned short st[64][264];
    int t = threadIdx.x;
    int blk = blockIdx.x;                 // 2 * 625
    int b = blk / 625, pix0 = (blk % 625) * 64;
    const float* xb = x + (size_t)b * CIN * NPIX + pix0;
    int p = t & 63, oct = t >> 6;

    for (int c32 = 0; c32 < CIN; c32 += 32) {
        int c = c32 + oct * 8;
        union { unsigned short u[8]; float4 f; } pk;
#pragma unroll
        for (int i = 0; i < 8; i++)
            pk.u[i] = bf16bits(xb[(size_t)(c + i) * NPIX + p]);
        *(float4*)&st[p][c] = pk.f;
    }
    __syncthreads();
    int p2 = t >> 2, qo = t & 3;
    unsigned short* dst = xT + ((size_t)b * NPIX + pix0 + p2) * CIN + qo * 64;
#pragma unroll
    for (int j = 0; j < 8; j++)
        *(float4*)(dst + j * 8) = *(const float4*)&st[p2][qo * 64 + j * 8];
}

// ---------------------------------------------------------------------------
// P1: w_om [108][256][3][3] fp32 -> wom3 bf16, A-fragment-contiguous layout:
//   wom3[(it*2+ks)][oc][quad][8], it = tap*4 + c64, slice = 128 oc * 32 = 4096 shorts.
//   Element (slice, oc, qj) = w[oc][c64*64 + ks*32 + qj][tap]  (oc >= 108 -> 0)
__global__ void prep_wom(const float* __restrict__ w, unsigned short* __restrict__ wom3) {
    int i = blockIdx.x * 256 + threadIdx.x;   // i < 72*4096 = 294912
    int slice = i >> 12, rem = i & 4095;
    int oc = rem >> 5, qj = rem & 31;
    int ks = slice & 1, it = slice >> 1;
    int tap = it >> 2, c64 = it & 3;
    int c = c64 * 64 + ks * 32 + qj;
    float v = (oc < OMCH) ? w[(size_t)oc * 2304 + c * 9 + tap] : 0.f;
    wom3[i] = bf16bits(v);
}

// P2: w_dcn [256][256][3][3] fp32 -> wt3 bf16, A-fragment-contiguous layout:
//   wt3[(gk*2+ks)][oc][quad][8], slice = 256 oc * 32 = 8192 shorts.
//   Element (slice, oc, qj) = w[oc][g*64 + ks*32 + qj][kk], g = gk/9, kk = gk%9
__global__ void prep_wdcn(const float* __restrict__ w, unsigned short* __restrict__ wt3) {
    int i = blockIdx.x * 256 + threadIdx.x;   // i < 72*8192 = 589824
    int slice = i >> 13, rem = i & 8191;
    int oc = rem >> 5, qj = rem & 31;
    int ks = slice & 1, gk = slice >> 1;
    int g = gk / 9, kk = gk % 9;
    int cin = g * 64 + ks * 32 + qj;
    wt3[i] = bf16bits(w[(size_t)oc * 2304 + cin * 9 + kk]);
}

// ---------------------------------------------------------------------------
// K1: om conv via bf16 MFMA. 512 thr / 8 waves, 128 px/block.
// Waves: (wv&3) -> oc quarter, (wv>>2) -> pixel half (64 px each).
// 36 iters: tap (9) x 64-ch chunk (4); stage v[64c][128p] from xT, pipelined.
// XCD-chunked block swizzle; weights in A-fragment-contiguous wom3 layout.
__global__ __launch_bounds__(512, 6) void om_mfma(const unsigned short* __restrict__ xT,
                                                  const unsigned short* __restrict__ wom3,
                                                  const float* __restrict__ bom,
                                                  float* __restrict__ om) {
    __shared__ __align__(16) unsigned short vbuf[2][128][72];  // [p][64c + 8 pad] = 36864 B

    int t = threadIdx.x;
    int p4 = t >> 2;                      // staging pixel 0..127
    int c4 = t & 3;                       // staging chunk 0..3
    int lane = t & 63, n16 = t & 15, quad = lane >> 4, wv = t >> 6;
    int ocbase = (wv & 3) * 32;
    int ph = (wv >> 2) * 64;

    int gp0 = xcd_swizzle(blockIdx.x, 625) * 128;  // 625 blocks over 80000 flat pixels
    int sp = gp0 + p4;                    // staging flat pixel (may straddle batch)
    int sb = (sp >= NPIX) ? 1 : 0;
    int srem = sp - sb * NPIX;
    int sh = srem / WW, sw = srem % WW;
    const unsigned short* xtb = xT + (size_t)sb * NPIX * CIN;

    floatx4 acc[2][4];
#pragma unroll
    for (int i = 0; i < 2; i++)
#pragma unroll
        for (int j = 0; j < 4; j++) acc[i][j] = (floatx4){0.f, 0.f, 0.f, 0.f};

    // stage it=0 (tap 0: di=-1,dj=-1; c0=0)
    {
        int h2 = sh - 1, w2 = sw - 1;
        bool valid = ((unsigned)h2 < (unsigned)HH) && ((unsigned)w2 < (unsigned)WW);
        float4 fa = {0.f,0.f,0.f,0.f}, fb = {0.f,0.f,0.f,0.f};
        if (valid) {
            const unsigned short* src = xtb + (size_t)(h2 * WW + w2) * CIN + c4 * 8;
            fa = *(const float4*)src;
            fb = *(const float4*)(src + 32);
        }
        *(float4*)&vbuf[0][p4][c4 * 8]      = fa;
        *(float4*)&vbuf[0][p4][32 + c4 * 8] = fb;
    }
    __syncthreads();

    for (int it = 0; it < 36; it++) {
        int cur = it & 1;
        bool have = (it < 35);

        // --- prefetch next staging chunk into registers ---
        float4 nfa = {0.f,0.f,0.f,0.f}, nfb = {0.f,0.f,0.f,0.f};
        if (have) {
            int itn = it + 1;
            int tapn = itn >> 2, c0n = (itn & 3) << 6;
            int h2 = sh + tapn / 3 - 1, w2 = sw + tapn % 3 - 1;
            bool valid = ((unsigned)h2 < (unsigned)HH) && ((unsigned)w2 < (unsigned)WW);
            if (valid) {
                const unsigned short* src = xtb + (size_t)(h2 * WW + w2) * CIN + c0n + c4 * 8;
                nfa = *(const float4*)src;
                nfb = *(const float4*)(src + 32);
            }
        }

        // --- MFMA phase (weights from wom3: slice (it*2+ks), 1 KB contiguous per a-load) ---
#pragma unroll
        for (int ks = 0; ks < 2; ks++) {
            bf16x8 bf0 = *(const bf16x8*)&vbuf[cur][ph + n16     ][ks * 32 + quad * 8];
            bf16x8 bf1 = *(const bf16x8*)&vbuf[cur][ph + 16 + n16][ks * 32 + quad * 8];
            bf16x8 bf2 = *(const bf16x8*)&vbuf[cur][ph + 32 + n16][ks * 32 + quad * 8];
            bf16x8 bf3 = *(const bf16x8*)&vbuf[cur][ph + 48 + n16][ks * 32 + quad * 8];
#pragma unroll
            for (int oi = 0; oi < 2; oi++) {
                bf16x8 a = *(const bf16x8*)&wom3[(size_t)(it * 2 + ks) * 4096
                                                 + (ocbase + oi * 16 + n16) * 32 + quad * 8];
                acc[oi][0] = __builtin_amdgcn_mfma_f32_16x16x32_bf16(a, bf0, acc[oi][0], 0, 0, 0);
                acc[oi][1] = __builtin_amdgcn_mfma_f32_16x16x32_bf16(a, bf1, acc[oi][1], 0, 0, 0);
                acc[oi][2] = __builtin_amdgcn_mfma_f32_16x16x32_bf16(a, bf2, acc[oi][2], 0, 0, 0);
                acc[oi][3] = __builtin_amdgcn_mfma_f32_16x16x32_bf16(a, bf3, acc[oi][3], 0, 0, 0);
            }
        }

        if (have) {
            *(float4*)&vbuf[cur ^ 1][p4][c4 * 8]      = nfa;
            *(float4*)&vbuf[cur ^ 1][p4][32 + c4 * 8] = nfb;
            __syncthreads();
        }
    }

    // epilogue: D col = n16 (pixel), row = quad*4+r (oc); + bias
#pragma unroll
    for (int oi = 0; oi < 2; oi++) {
        int oc0 = ocbase + oi * 16 + quad * 4;
        if (oc0 < OMCH) {
#pragma unroll
            for (int pt = 0; pt < 4; pt++) {
                int fp = gp0 + ph + pt * 16 + n16;
                int bq = (fp >= NPIX) ? 1 : 0;
                int rem = fp - bq * NPIX;
#pragma unroll
                for (int r = 0; r < 4; r++) {
                    int occ = oc0 + r;
                    if (occ < OMCH)
                        om[((size_t)(bq * OMCH + occ)) * NPIX + rem] = acc[oi][pt][r] + bom[occ];
                }
            }
        }
    }
}

// ---------------------------------------------------------------------------
// K2: fused DCN. 512 thr / 8 waves, 64 px/block. Wave wv -> oc [32wv, +32).
// Params packed to 12 B/record in LDS (46 KB total -> 3 blocks/CU).
// Pipeline: parm(gk+2) LDS-read || gather(gk+1) || MFMA(gk) || pack(gk+1).
// XCD-chunked block swizzle; weights in A-fragment-contiguous wt3 layout.
__global__ __launch_bounds__(512, 6) void dcn_mfma(const unsigned short* __restrict__ xT,
                                                   const float* __restrict__ om,
                                                   const unsigned short* __restrict__ wt3,
                                                   float* __restrict__ out) {
    __shared__ unsigned int iPk[36 * 64];                    //  9216 B: i00 | dx1<<16 | dy1<<17
    __shared__ uint2        wPk[36 * 64];                    // 18432 B: 4 x bf16 corner weights
    __shared__ __align__(16) unsigned short vbuf[2][64][72]; // 18432 B

    int t = threadIdx.x;
    int l = t & 63;
    int oct = t >> 6;             // wave id
    int p8 = l >> 3;              // pixel sub-index within wave
    int chunk = l & 7;            // 16B channel chunk
    int mypix = oct * 8 + p8;     // staging pixel 0..63
    int n16 = t & 15, quad = l >> 4;
    int ocbase = oct * 32;

    int gp0 = xcd_swizzle(blockIdx.x, 1250) * 64;  // 1250 blocks; 40000 % 64 == 0
    int b = gp0 / NPIX;
    int pix0 = gp0 - b * NPIX;
    const unsigned short* xtb = xT + (size_t)b * NPIX * CIN;
    const float* omb = om + (size_t)b * OMCH * NPIX;

    // ---- prologue: packed sampling params for all (gk, p) ----
    for (int r = t; r < 36 * 64; r += 512) {
        int gk = r >> 6, p = r & 63;
        int g = gk / 9, kk = gk % 9;
        int ki = kk / 3, kj = kk % 3;
        int pp = pix0 + p;
        int hh = pp / WW, ww2 = pp % WW;
        float dy = omb[(size_t)(g * 18 + 2 * kk    ) * NPIX + pp];
        float dx = omb[(size_t)(g * 18 + 2 * kk + 1) * NPIX + pp];
        float mr = omb[(size_t)(72 + g * 9 + kk    ) * NPIX + pp];
        float m = 1.f / (1.f + __expf(-mr));
        float py = (float)(hh - 1 + ki) + dy;
        float px = (float)(ww2 - 1 + kj) + dx;
        float fy = floorf(py), fx = floorf(px);
        float wy = py - fy, wx = px - fx;
        int y0 = (int)fy, x0 = (int)fx, y1 = y0 + 1, x1 = x0 + 1;
        bool vy0 = (y0 >= 0) && (y0 < HH), vy1 = (y1 >= 0) && (y1 < HH);
        bool vx0 = (x0 >= 0) && (x0 < WW), vx1 = (x1 >= 0) && (x1 < WW);
        int cy0 = min(max(y0, 0), HH - 1), cy1 = min(max(y1, 0), HH - 1);
        int cx0 = min(max(x0, 0), WW - 1), cx1 = min(max(x1, 0), WW - 1);
        float w00 = (vy0 && vx0) ? (1.f - wy) * (1.f - wx) * m : 0.f;
        float w01 = (vy0 && vx1) ? (1.f - wy) * wx * m : 0.f;
        float w10 = (vy1 && vx0) ? wy * (1.f - wx) * m : 0.f;
        float w11 = (vy1 && vx1) ? wy * wx * m : 0.f;
        int i00 = cy0 * WW + cx0;
        unsigned int dx1 = (unsigned int)(cx1 - cx0);   // 0/1
        unsigned int dy1 = (unsigned int)(cy1 - cy0);   // 0/1
        iPk[r] = (unsigned int)i00 | (dx1 << 16) | (dy1 << 17);
        uint2 wp;
        wp.x = (unsigned int)bf16bits(w00) | ((unsigned int)bf16bits(w01) << 16);
        wp.y = (unsigned int)bf16bits(w10) | ((unsigned int)bf16bits(w11) << 16);
        wPk[r] = wp;
    }
    __syncthreads();

    floatx4 acc[2][4];
#pragma unroll
    for (int i = 0; i < 2; i++)
#pragma unroll
        for (int j = 0; j < 4; j++) acc[i][j] = (floatx4){0.f, 0.f, 0.f, 0.f};

    unsigned int ipNext; uint2 wpNext;   // params for the NEXT gather iteration

    // ---- stage gk = 0 (and preload parm(1)) ----
    {
        unsigned int ip = iPk[mypix];
        uint2 wp = wPk[mypix];
        int i00 = ip & 0xffff;
        int dx1 = (ip >> 16) & 1, dy1 = (ip >> 17) & 1;
        int i01 = i00 + dx1, i10 = i00 + dy1 * WW, i11 = i10 + dx1;
        const unsigned short* xg = xtb + chunk * 8;     // g = 0
        bf16x8 c00 = *(const bf16x8*)(xg + (size_t)i00 * CIN);
        bf16x8 c01 = *(const bf16x8*)(xg + (size_t)i01 * CIN);
        bf16x8 c10 = *(const bf16x8*)(xg + (size_t)i10 * CIN);
        bf16x8 c11 = *(const bf16x8*)(xg + (size_t)i11 * CIN);
        ipNext = iPk[64 + mypix];
        wpNext = wPk[64 + mypix];
        float w00 = lo_bf(wp.x), w01 = hi_bf(wp.x);
        float w10 = lo_bf(wp.y), w11 = hi_bf(wp.y);
        union { unsigned short u[8]; float4 f; } pk;
#pragma unroll
        for (int i = 0; i < 8; i++) {
            float v = w00 * (float)c00[i] + w01 * (float)c01[i]
                    + w10 * (float)c10[i] + w11 * (float)c11[i];
            pk.u[i] = bf16bits(v);
        }
        *(float4*)&vbuf[0][mypix][chunk * 8] = pk.f;
    }
    __syncthreads();

    for (int gk = 0; gk < 36; gk++) {
        int cur = gk & 1;
        bool have = (gk < 35);

        // --- gather gk+1 using pre-loaded params (addresses register-ready) ---
        float nw00, nw01, nw10, nw11;
        bf16x8 n00, n01, n10, n11;
        if (have) {
            unsigned int ip = ipNext; uint2 wp = wpNext;
            int i00 = ip & 0xffff;
            int dx1 = (ip >> 16) & 1, dy1 = (ip >> 17) & 1;
            int i01 = i00 + dx1, i10 = i00 + dy1 * WW, i11 = i10 + dx1;
            const unsigned short* xg = xtb + ((gk + 1) / 9) * 64 + chunk * 8;
            n00 = *(const bf16x8*)(xg + (size_t)i00 * CIN);
            n01 = *(const bf16x8*)(xg + (size_t)i01 * CIN);
            n10 = *(const bf16x8*)(xg + (size_t)i10 * CIN);
            n11 = *(const bf16x8*)(xg + (size_t)i11 * CIN);
            nw00 = lo_bf(wp.x); nw01 = hi_bf(wp.x);
            nw10 = lo_bf(wp.y); nw11 = hi_bf(wp.y);
        }
        // --- preload params for gk+2 (decoupled from next iter's gather) ---
        if (gk < 34) {
            ipNext = iPk[(gk + 2) * 64 + mypix];
            wpNext = wPk[(gk + 2) * 64 + mypix];
        }

        // --- MFMA phase (gk); weights from wt3: slice (gk*2+ks), contiguous a-loads ---
#pragma unroll
        for (int ks = 0; ks < 2; ks++) {
            bf16x8 bf0 = *(const bf16x8*)&vbuf[cur][n16     ][ks * 32 + quad * 8];
            bf16x8 bf1 = *(const bf16x8*)&vbuf[cur][16 + n16][ks * 32 + quad * 8];
            bf16x8 bf2 = *(const bf16x8*)&vbuf[cur][32 + n16][ks * 32 + quad * 8];
            bf16x8 bf3 = *(const bf16x8*)&vbuf[cur][48 + n16][ks * 32 + quad * 8];
#pragma unroll
            for (int oi = 0; oi < 2; oi++) {
                bf16x8 a = *(const bf16x8*)&wt3[(size_t)(gk * 2 + ks) * 8192
                                                + (ocbase + oi * 16 + n16) * 32 + quad * 8];
                acc[oi][0] = __builtin_amdgcn_mfma_f32_16x16x32_bf16(a, bf0, acc[oi][0], 0, 0, 0);
                acc[oi][1] = __builtin_amdgcn_mfma_f32_16x16x32_bf16(a, bf1, acc[oi][1], 0, 0, 0);
                acc[oi][2] = __builtin_amdgcn_mfma_f32_16x16x32_bf16(a, bf2, acc[oi][2], 0, 0, 0);
                acc[oi][3] = __builtin_amdgcn_mfma_f32_16x16x32_bf16(a, bf3, acc[oi][3], 0, 0, 0);
            }
        }

        if (have) {
            union { unsigned short u[8]; float4 f; } pk;
#pragma unroll
            for (int i = 0; i < 8; i++) {
                float v = nw00 * (float)n00[i] + nw01 * (float)n01[i]
                        + nw10 * (float)n10[i] + nw11 * (float)n11[i];
                pk.u[i] = bf16bits(v);
            }
            *(float4*)&vbuf[cur ^ 1][mypix][chunk * 8] = pk.f;
            __syncthreads();
        }
    }

    // ---- epilogue: ReLU + store ----
#pragma unroll
    for (int oi = 0; oi < 2; oi++)
#pragma unroll
        for (int pt = 0; pt < 4; pt++) {
            int gpix = pix0 + pt * 16 + n16;
#pragma unroll
            for (int r = 0; r < 4; r++) {
                int oc = ocbase + oi * 16 + quad * 4 + r;
                out[((size_t)(b * OCH + oc)) * NPIX + gpix] = fmaxf(acc[oi][pt][r], 0.f);
            }
        }
}

// ---------------------------------------------------------------------------
extern "C" void kernel_launch(void* const* d_in, const int* in_sizes, int n_in,
                              void* d_out, int out_size, void* d_ws, size_t ws_size,
                              hipStream_t stream) {
    const float* x     = (const float*)d_in[0];
    const float* w_om  = (const float*)d_in[1];
    const float* b_om  = (const float*)d_in[2];
    const float* w_dcn = (const float*)d_in[3];
    float* out = (float*)d_out;

    // workspace layout (77.3 MB total)
    char* ws = (char*)d_ws;
    float*          om   = (float*)(ws);                         // 34,560,000 B
    unsigned short* xT   = (unsigned short*)(ws + 34560000);     // 40,960,000 B
    unsigned short* wom3 = (unsigned short*)(ws + 75520000);     //    589,824 B
    unsigned short* wt3  = (unsigned short*)(ws + 76109824);     //  1,179,648 B

    transpose_x<<<1250, 256, 0, stream>>>(x, xT);
    prep_wom   <<<1152, 256, 0, stream>>>(w_om, wom3);
    prep_wdcn  <<<2304, 256, 0, stream>>>(w_dcn, wt3);
    om_mfma    <<< 625, 512, 0, stream>>>(xT, wom3, b_om, om);
    dcn_mfma   <<<1250, 512, 0, stream>>>(xT, om, wt3, out);
}

// Round 7
// 397.807 us; speedup vs baseline: 2.7685x; 1.0329x over previous
//
#include <hip/hip_runtime.h>
#include <math.h>

// Problem constants
#define HH 200
#define WW 200
#define CIN 256
#define OMCH 108   // 72 offset + 36 mask
#define OCH 256
#define NPIX (HH*WW)

typedef _Float16 f16x8 __attribute__((ext_vector_type(8)));
typedef float floatx4 __attribute__((ext_vector_type(4)));

static __device__ __forceinline__ unsigned short f16bits(float v) {
    _Float16 h = (_Float16)v;
    return __builtin_bit_cast(unsigned short, h);
}
static __device__ __forceinline__ _Float16 f16lo(unsigned int u) {
    return __builtin_bit_cast(_Float16, (unsigned short)(u & 0xffffu));
}
static __device__ __forceinline__ _Float16 f16hi(unsigned int u) {
    return __builtin_bit_cast(_Float16, (unsigned short)(u >> 16));
}

// Bijective XCD-chunked swizzle (m204): HW assigns block b -> XCD b%8 round-robin.
// Remap so each XCD processes a CONTIGUOUS chunk of work ids -> xT row neighborhoods
// stay resident in that XCD's private L2 instead of being fetched by all 8.
static __device__ __forceinline__ int xcd_swizzle(int orig, int nwg) {
    int q = nwg >> 3, r = nwg & 7;
    int x = orig & 7, rank = orig >> 3;
    int base = (x < r) ? x * (q + 1) : r * (q + 1) + (x - r) * q;
    return base + rank;
}

// ---------------------------------------------------------------------------
// P0: x [B][C][HW] fp32 -> xT [B][HW][C] f16.  64-pixel tiles, LDS transpose.
__global__ __launch_bounds__(256) void transpose_x(const float* __restrict__ x,
                                                   unsigned short* __restrict__ xT) {
    __shared__ __align__(16) unsigned short st[64][264];
    int t = threadIdx.x;
    int blk = blockIdx.x;                 // 2 * 625
    int b = blk / 625, pix0 = (blk % 625) * 64;
    const float* xb = x + (size_t)b * CIN * NPIX + pix0;
    int p = t & 63, oct = t >> 6;

    for (int c32 = 0; c32 < CIN; c32 += 32) {
        int c = c32 + oct * 8;
        union { unsigned short u[8]; float4 f; } pk;
#pragma unroll
        for (int i = 0; i < 8; i++)
            pk.u[i] = f16bits(xb[(size_t)(c + i) * NPIX + p]);
        *(float4*)&st[p][c] = pk.f;
    }
    __syncthreads();
    int p2 = t >> 2, qo = t & 3;
    unsigned short* dst = xT + ((size_t)b * NPIX + pix0 + p2) * CIN + qo * 64;
#pragma unroll
    for (int j = 0; j < 8; j++)
        *(float4*)(dst + j * 8) = *(const float4*)&st[p2][qo * 64 + j * 8];
}

// ---------------------------------------------------------------------------
// P1: w_om [108][256][3][3] fp32 -> wom3 f16, A-fragment-contiguous layout:
//   wom3[(it*2+ks)][oc][quad][8], it = tap*4 + c64, slice = 128 oc * 32 = 4096 shorts.
//   Element (slice, oc, qj) = w[oc][c64*64 + ks*32 + qj][tap]  (oc >= 108 -> 0)
__global__ void prep_wom(const float* __restrict__ w, unsigned short* __restrict__ wom3) {
    int i = blockIdx.x * 256 + threadIdx.x;   // i < 72*4096 = 294912
    int slice = i >> 12, rem = i & 4095;
    int oc = rem >> 5, qj = rem & 31;
    int ks = slice & 1, it = slice >> 1;
    int tap = it >> 2, c64 = it & 3;
    int c = c64 * 64 + ks * 32 + qj;
    float v = (oc < OMCH) ? w[(size_t)oc * 2304 + c * 9 + tap] : 0.f;
    wom3[i] = f16bits(v);
}

// P2: w_dcn [256][256][3][3] fp32 -> wt3 f16, A-fragment-contiguous layout:
//   wt3[(gk*2+ks)][oc][quad][8], slice = 256 oc * 32 = 8192 shorts.
//   Element (slice, oc, qj) = w[oc][g*64 + ks*32 + qj][kk], g = gk/9, kk = gk%9
__global__ void prep_wdcn(const float* __restrict__ w, unsigned short* __restrict__ wt3) {
    int i = blockIdx.x * 256 + threadIdx.x;   // i < 72*8192 = 589824
    int slice = i >> 13, rem = i & 8191;
    int oc = rem >> 5, qj = rem & 31;
    int ks = slice & 1, gk = slice >> 1;
    int g = gk / 9, kk = gk % 9;
    int cin = g * 64 + ks * 32 + qj;
    wt3[i] = f16bits(w[(size_t)oc * 2304 + cin * 9 + kk]);
}

// ---------------------------------------------------------------------------
// K1: om conv via f16 MFMA. 512 thr / 8 waves, 128 px/block.
// Waves: (wv&3) -> oc quarter, (wv>>2) -> pixel half (64 px each).
// 36 iters: tap (9) x 64-ch chunk (4); stage v[64c][128p] from xT, pipelined.
// XCD-chunked block swizzle; weights in A-fragment-contiguous wom3 layout.
__global__ __launch_bounds__(512, 6) void om_mfma(const unsigned short* __restrict__ xT,
                                                  const unsigned short* __restrict__ wom3,
                                                  const float* __restrict__ bom,
                                                  float* __restrict__ om) {
    __shared__ __align__(16) unsigned short vbuf[2][128][72];  // [p][64c + 8 pad] = 36864 B

    int t = threadIdx.x;
    int p4 = t >> 2;                      // staging pixel 0..127
    int c4 = t & 3;                       // staging chunk 0..3
    int lane = t & 63, n16 = t & 15, quad = lane >> 4, wv = t >> 6;
    int ocbase = (wv & 3) * 32;
    int ph = (wv >> 2) * 64;

    int gp0 = xcd_swizzle(blockIdx.x, 625) * 128;  // 625 blocks over 80000 flat pixels
    int sp = gp0 + p4;                    // staging flat pixel (may straddle batch)
    int sb = (sp >= NPIX) ? 1 : 0;
    int srem = sp - sb * NPIX;
    int sh = srem / WW, sw = srem % WW;
    const unsigned short* xtb = xT + (size_t)sb * NPIX * CIN;

    floatx4 acc[2][4];
#pragma unroll
    for (int i = 0; i < 2; i++)
#pragma unroll
        for (int j = 0; j < 4; j++) acc[i][j] = (floatx4){0.f, 0.f, 0.f, 0.f};

    // stage it=0 (tap 0: di=-1,dj=-1; c0=0)
    {
        int h2 = sh - 1, w2 = sw - 1;
        bool valid = ((unsigned)h2 < (unsigned)HH) && ((unsigned)w2 < (unsigned)WW);
        float4 fa = {0.f,0.f,0.f,0.f}, fb = {0.f,0.f,0.f,0.f};
        if (valid) {
            const unsigned short* src = xtb + (size_t)(h2 * WW + w2) * CIN + c4 * 8;
            fa = *(const float4*)src;
            fb = *(const float4*)(src + 32);
        }
        *(float4*)&vbuf[0][p4][c4 * 8]      = fa;
        *(float4*)&vbuf[0][p4][32 + c4 * 8] = fb;
    }
    __syncthreads();

    for (int it = 0; it < 36; it++) {
        int cur = it & 1;
        bool have = (it < 35);

        // --- prefetch next staging chunk into registers ---
        float4 nfa = {0.f,0.f,0.f,0.f}, nfb = {0.f,0.f,0.f,0.f};
        if (have) {
            int itn = it + 1;
            int tapn = itn >> 2, c0n = (itn & 3) << 6;
            int h2 = sh + tapn / 3 - 1, w2 = sw + tapn % 3 - 1;
            bool valid = ((unsigned)h2 < (unsigned)HH) && ((unsigned)w2 < (unsigned)WW);
            if (valid) {
                const unsigned short* src = xtb + (size_t)(h2 * WW + w2) * CIN + c0n + c4 * 8;
                nfa = *(const float4*)src;
                nfb = *(const float4*)(src + 32);
            }
        }

        // --- MFMA phase (weights from wom3: slice (it*2+ks), 1 KB contiguous per a-load) ---
#pragma unroll
        for (int ks = 0; ks < 2; ks++) {
            f16x8 bf0 = *(const f16x8*)&vbuf[cur][ph + n16     ][ks * 32 + quad * 8];
            f16x8 bf1 = *(const f16x8*)&vbuf[cur][ph + 16 + n16][ks * 32 + quad * 8];
            f16x8 bf2 = *(const f16x8*)&vbuf[cur][ph + 32 + n16][ks * 32 + quad * 8];
            f16x8 bf3 = *(const f16x8*)&vbuf[cur][ph + 48 + n16][ks * 32 + quad * 8];
#pragma unroll
            for (int oi = 0; oi < 2; oi++) {
                f16x8 a = *(const f16x8*)&wom3[(size_t)(it * 2 + ks) * 4096
                                               + (ocbase + oi * 16 + n16) * 32 + quad * 8];
                acc[oi][0] = __builtin_amdgcn_mfma_f32_16x16x32_f16(a, bf0, acc[oi][0], 0, 0, 0);
                acc[oi][1] = __builtin_amdgcn_mfma_f32_16x16x32_f16(a, bf1, acc[oi][1], 0, 0, 0);
                acc[oi][2] = __builtin_amdgcn_mfma_f32_16x16x32_f16(a, bf2, acc[oi][2], 0, 0, 0);
                acc[oi][3] = __builtin_amdgcn_mfma_f32_16x16x32_f16(a, bf3, acc[oi][3], 0, 0, 0);
            }
        }

        if (have) {
            *(float4*)&vbuf[cur ^ 1][p4][c4 * 8]      = nfa;
            *(float4*)&vbuf[cur ^ 1][p4][32 + c4 * 8] = nfb;
            __syncthreads();
        }
    }

    // epilogue: D col = n16 (pixel), row = quad*4+r (oc); + bias
#pragma unroll
    for (int oi = 0; oi < 2; oi++) {
        int oc0 = ocbase + oi * 16 + quad * 4;
        if (oc0 < OMCH) {
#pragma unroll
            for (int pt = 0; pt < 4; pt++) {
                int fp = gp0 + ph + pt * 16 + n16;
                int bq = (fp >= NPIX) ? 1 : 0;
                int rem = fp - bq * NPIX;
#pragma unroll
                for (int r = 0; r < 4; r++) {
                    int occ = oc0 + r;
                    if (occ < OMCH)
                        om[((size_t)(bq * OMCH + occ)) * NPIX + rem] = acc[oi][pt][r] + bom[occ];
                }
            }
        }
    }
}

// ---------------------------------------------------------------------------
// K2: fused DCN. 512 thr / 8 waves, 64 px/block. Wave wv -> oc [32wv, +32).
// Params packed to 12 B/record in LDS (46 KB total -> 3 blocks/CU).
// Pipeline: parm(gk+2) LDS-read || gather(gk+1) || MFMA(gk) || pack(gk+1).
// XCD-chunked block swizzle; wt3 A-fragment-contiguous; bilinear pack in
// packed-f16 VALU (v_pk_fma_f16) -- no scalar converts.
__global__ __launch_bounds__(512, 6) void dcn_mfma(const unsigned short* __restrict__ xT,
                                                   const float* __restrict__ om,
                                                   const unsigned short* __restrict__ wt3,
                                                   float* __restrict__ out) {
    __shared__ unsigned int iPk[36 * 64];                    //  9216 B: i00 | dx1<<16 | dy1<<17
    __shared__ uint2        wPk[36 * 64];                    // 18432 B: 4 x f16 corner weights
    __shared__ __align__(16) unsigned short vbuf[2][64][72]; // 18432 B

    int t = threadIdx.x;
    int l = t & 63;
    int oct = t >> 6;             // wave id
    int p8 = l >> 3;              // pixel sub-index within wave
    int chunk = l & 7;            // 16B channel chunk
    int mypix = oct * 8 + p8;     // staging pixel 0..63
    int n16 = t & 15, quad = l >> 4;
    int ocbase = oct * 32;

    int gp0 = xcd_swizzle(blockIdx.x, 1250) * 64;  // 1250 blocks; 40000 % 64 == 0
    int b = gp0 / NPIX;
    int pix0 = gp0 - b * NPIX;
    const unsigned short* xtb = xT + (size_t)b * NPIX * CIN;
    const float* omb = om + (size_t)b * OMCH * NPIX;

    // ---- prologue: packed sampling params for all (gk, p) ----
    for (int r = t; r < 36 * 64; r += 512) {
        int gk = r >> 6, p = r & 63;
        int g = gk / 9, kk = gk % 9;
        int ki = kk / 3, kj = kk % 3;
        int pp = pix0 + p;
        int hh = pp / WW, ww2 = pp % WW;
        float dy = omb[(size_t)(g * 18 + 2 * kk    ) * NPIX + pp];
        float dx = omb[(size_t)(g * 18 + 2 * kk + 1) * NPIX + pp];
        float mr = omb[(size_t)(72 + g * 9 + kk    ) * NPIX + pp];
        float m = 1.f / (1.f + __expf(-mr));
        float py = (float)(hh - 1 + ki) + dy;
        float px = (float)(ww2 - 1 + kj) + dx;
        float fy = floorf(py), fx = floorf(px);
        float wy = py - fy, wx = px - fx;
        int y0 = (int)fy, x0 = (int)fx, y1 = y0 + 1, x1 = x0 + 1;
        bool vy0 = (y0 >= 0) && (y0 < HH), vy1 = (y1 >= 0) && (y1 < HH);
        bool vx0 = (x0 >= 0) && (x0 < WW), vx1 = (x1 >= 0) && (x1 < WW);
        int cy0 = min(max(y0, 0), HH - 1), cy1 = min(max(y1, 0), HH - 1);
        int cx0 = min(max(x0, 0), WW - 1), cx1 = min(max(x1, 0), WW - 1);
        float w00 = (vy0 && vx0) ? (1.f - wy) * (1.f - wx) * m : 0.f;
        float w01 = (vy0 && vx1) ? (1.f - wy) * wx * m : 0.f;
        float w10 = (vy1 && vx0) ? wy * (1.f - wx) * m : 0.f;
        float w11 = (vy1 && vx1) ? wy * wx * m : 0.f;
        int i00 = cy0 * WW + cx0;
        unsigned int dx1 = (unsigned int)(cx1 - cx0);   // 0/1
        unsigned int dy1 = (unsigned int)(cy1 - cy0);   // 0/1
        iPk[r] = (unsigned int)i00 | (dx1 << 16) | (dy1 << 17);
        uint2 wp;
        wp.x = (unsigned int)f16bits(w00) | ((unsigned int)f16bits(w01) << 16);
        wp.y = (unsigned int)f16bits(w10) | ((unsigned int)f16bits(w11) << 16);
        wPk[r] = wp;
    }
    __syncthreads();

    floatx4 acc[2][4];
#pragma unroll
    for (int i = 0; i < 2; i++)
#pragma unroll
        for (int j = 0; j < 4; j++) acc[i][j] = (floatx4){0.f, 0.f, 0.f, 0.f};

    unsigned int ipNext; uint2 wpNext;   // params for the NEXT gather iteration

    // ---- stage gk = 0 (and preload parm(1)) ----
    {
        unsigned int ip = iPk[mypix];
        uint2 wp = wPk[mypix];
        int i00 = ip & 0xffff;
        int dx1 = (ip >> 16) & 1, dy1 = (ip >> 17) & 1;
        int i01 = i00 + dx1, i10 = i00 + dy1 * WW, i11 = i10 + dx1;
        const unsigned short* xg = xtb + chunk * 8;     // g = 0
        f16x8 c00 = *(const f16x8*)(xg + (size_t)i00 * CIN);
        f16x8 c01 = *(const f16x8*)(xg + (size_t)i01 * CIN);
        f16x8 c10 = *(const f16x8*)(xg + (size_t)i10 * CIN);
        f16x8 c11 = *(const f16x8*)(xg + (size_t)i11 * CIN);
        ipNext = iPk[64 + mypix];
        wpNext = wPk[64 + mypix];
        f16x8 v = c00 * f16lo(wp.x) + c01 * f16hi(wp.x)
                + c10 * f16lo(wp.y) + c11 * f16hi(wp.y);
        *(float4*)&vbuf[0][mypix][chunk * 8] = __builtin_bit_cast(float4, v);
    }
    __syncthreads();

    for (int gk = 0; gk < 36; gk++) {
        int cur = gk & 1;
        bool have = (gk < 35);

        // --- gather gk+1 using pre-loaded params (addresses register-ready) ---
        _Float16 nw00, nw01, nw10, nw11;
        f16x8 n00, n01, n10, n11;
        if (have) {
            unsigned int ip = ipNext; uint2 wp = wpNext;
            int i00 = ip & 0xffff;
            int dx1 = (ip >> 16) & 1, dy1 = (ip >> 17) & 1;
            int i01 = i00 + dx1, i10 = i00 + dy1 * WW, i11 = i10 + dx1;
            const unsigned short* xg = xtb + ((gk + 1) / 9) * 64 + chunk * 8;
            n00 = *(const f16x8*)(xg + (size_t)i00 * CIN);
            n01 = *(const f16x8*)(xg + (size_t)i01 * CIN);
            n10 = *(const f16x8*)(xg + (size_t)i10 * CIN);
            n11 = *(const f16x8*)(xg + (size_t)i11 * CIN);
            nw00 = f16lo(wp.x); nw01 = f16hi(wp.x);
            nw10 = f16lo(wp.y); nw11 = f16hi(wp.y);
        }
        // --- preload params for gk+2 (decoupled from next iter's gather) ---
        if (gk < 34) {
            ipNext = iPk[(gk + 2) * 64 + mypix];
            wpNext = wPk[(gk + 2) * 64 + mypix];
        }

        // --- MFMA phase (gk); weights from wt3: slice (gk*2+ks), contiguous a-loads ---
#pragma unroll
        for (int ks = 0; ks < 2; ks++) {
            f16x8 bf0 = *(const f16x8*)&vbuf[cur][n16     ][ks * 32 + quad * 8];
            f16x8 bf1 = *(const f16x8*)&vbuf[cur][16 + n16][ks * 32 + quad * 8];
            f16x8 bf2 = *(const f16x8*)&vbuf[cur][32 + n16][ks * 32 + quad * 8];
            f16x8 bf3 = *(const f16x8*)&vbuf[cur][48 + n16][ks * 32 + quad * 8];
#pragma unroll
            for (int oi = 0; oi < 2; oi++) {
                f16x8 a = *(const f16x8*)&wt3[(size_t)(gk * 2 + ks) * 8192
                                              + (ocbase + oi * 16 + n16) * 32 + quad * 8];
                acc[oi][0] = __builtin_amdgcn_mfma_f32_16x16x32_f16(a, bf0, acc[oi][0], 0, 0, 0);
                acc[oi][1] = __builtin_amdgcn_mfma_f32_16x16x32_f16(a, bf1, acc[oi][1], 0, 0, 0);
                acc[oi][2] = __builtin_amdgcn_mfma_f32_16x16x32_f16(a, bf2, acc[oi][2], 0, 0, 0);
                acc[oi][3] = __builtin_amdgcn_mfma_f32_16x16x32_f16(a, bf3, acc[oi][3], 0, 0, 0);
            }
        }

        if (have) {
            f16x8 v = n00 * nw00 + n01 * nw01 + n10 * nw10 + n11 * nw11;
            *(float4*)&vbuf[cur ^ 1][mypix][chunk * 8] = __builtin_bit_cast(float4, v);
            __syncthreads();
        }
    }

    // ---- epilogue: ReLU + store ----
#pragma unroll
    for (int oi = 0; oi < 2; oi++)
#pragma unroll
        for (int pt = 0; pt < 4; pt++) {
            int gpix = pix0 + pt * 16 + n16;
#pragma unroll
            for (int r = 0; r < 4; r++) {
                int oc = ocbase + oi * 16 + quad * 4 + r;
                out[((size_t)(b * OCH + oc)) * NPIX + gpix] = fmaxf(acc[oi][pt][r], 0.f);
            }
        }
}

// ---------------------------------------------------------------------------
extern "C" void kernel_launch(void* const* d_in, const int* in_sizes, int n_in,
                              void* d_out, int out_size, void* d_ws, size_t ws_size,
                              hipStream_t stream) {
    const float* x     = (const float*)d_in[0];
    const float* w_om  = (const float*)d_in[1];
    const float* b_om  = (const float*)d_in[2];
    const float* w_dcn = (const float*)d_in[3];
    float* out = (float*)d_out;

    // workspace layout (77.3 MB total)
    char* ws = (char*)d_ws;
    float*          om   = (float*)(ws);                         // 34,560,000 B
    unsigned short* xT   = (unsigned short*)(ws + 34560000);     // 40,960,000 B
    unsigned short* wom3 = (unsigned short*)(ws + 75520000);     //    589,824 B
    unsigned short* wt3  = (unsigned short*)(ws + 76109824);     //  1,179,648 B

    transpose_x<<<1250, 256, 0, stream>>>(x, xT);
    prep_wom   <<<1152, 256, 0, stream>>>(w_om, wom3);
    prep_wdcn  <<<2304, 256, 0, stream>>>(w_dcn, wt3);
    om_mfma    <<< 625, 512, 0, stream>>>(xT, wom3, b_om, om);
    dcn_mfma   <<<1250, 512, 0, stream>>>(xT, om, wt3, out);
}

// Round 9
// 394.120 us; speedup vs baseline: 2.7944x; 1.0094x over previous
//
#include <hip/hip_runtime.h>
#include <math.h>

// Problem constants
#define HH 200
#define WW 200
#define CIN 256
#define OMCH 108   // 72 offset + 36 mask
#define OCH 256
#define NPIX (HH*WW)

typedef _Float16 f16x8 __attribute__((ext_vector_type(8)));
typedef float floatx4 __attribute__((ext_vector_type(4)));

static __device__ __forceinline__ unsigned short f16bits(float v) {
    _Float16 h = (_Float16)v;
    return __builtin_bit_cast(unsigned short, h);
}
static __device__ __forceinline__ _Float16 f16lo(unsigned int u) {
    return __builtin_bit_cast(_Float16, (unsigned short)(u & 0xffffu));
}
static __device__ __forceinline__ _Float16 f16hi(unsigned int u) {
    return __builtin_bit_cast(_Float16, (unsigned short)(u >> 16));
}

// Bijective XCD-chunked swizzle (m204): HW assigns block b -> XCD b%8 round-robin.
// Remap so each XCD processes a CONTIGUOUS chunk of work ids -> xT row neighborhoods
// stay resident in that XCD's private L2 instead of being fetched by all 8.
static __device__ __forceinline__ int xcd_swizzle(int orig, int nwg) {
    int q = nwg >> 3, r = nwg & 7;
    int x = orig & 7, rank = orig >> 3;
    int base = (x < r) ? x * (q + 1) : r * (q + 1) + (x - r) * q;
    return base + rank;
}

// ---------------------------------------------------------------------------
// P0: x [B][C][HW] fp32 -> xT [B][HW][C] f16.  64-pixel tiles, LDS transpose.
__global__ __launch_bounds__(256) void transpose_x(const float* __restrict__ x,
                                                   unsigned short* __restrict__ xT) {
    __shared__ __align__(16) unsigned short st[64][264];
    int t = threadIdx.x;
    int blk = blockIdx.x;                 // 2 * 625
    int b = blk / 625, pix0 = (blk % 625) * 64;
    const float* xb = x + (size_t)b * CIN * NPIX + pix0;
    int p = t & 63, oct = t >> 6;

    for (int c32 = 0; c32 < CIN; c32 += 32) {
        int c = c32 + oct * 8;
        union { unsigned short u[8]; float4 f; } pk;
#pragma unroll
        for (int i = 0; i < 8; i++)
            pk.u[i] = f16bits(xb[(size_t)(c + i) * NPIX + p]);
        *(float4*)&st[p][c] = pk.f;
    }
    __syncthreads();
    int p2 = t >> 2, qo = t & 3;
    unsigned short* dst = xT + ((size_t)b * NPIX + pix0 + p2) * CIN + qo * 64;
#pragma unroll
    for (int j = 0; j < 8; j++)
        *(float4*)(dst + j * 8) = *(const float4*)&st[p2][qo * 64 + j * 8];
}

// ---------------------------------------------------------------------------
// P1: w_om [108][256][3][3] fp32 -> wom3 f16, A-fragment-contiguous layout:
//   wom3[(it*2+ks)][oc][quad][8], it = tap*4 + c64, slice = 128 oc * 32 = 4096 shorts.
//   Element (slice, oc, qj) = w[oc][c64*64 + ks*32 + qj][tap]  (oc >= 108 -> 0)
__global__ void prep_wom(const float* __restrict__ w, unsigned short* __restrict__ wom3) {
    int i = blockIdx.x * 256 + threadIdx.x;   // i < 72*4096 = 294912
    int slice = i >> 12, rem = i & 4095;
    int oc = rem >> 5, qj = rem & 31;
    int ks = slice & 1, it = slice >> 1;
    int tap = it >> 2, c64 = it & 3;
    int c = c64 * 64 + ks * 32 + qj;
    float v = (oc < OMCH) ? w[(size_t)oc * 2304 + c * 9 + tap] : 0.f;
    wom3[i] = f16bits(v);
}

// P2: w_dcn [256][256][3][3] fp32 -> wt3 f16, A-fragment-contiguous layout:
//   wt3[(gk*2+ks)][oc][quad][8], slice = 256 oc * 32 = 8192 shorts.
//   Element (slice, oc, qj) = w[oc][g*64 + ks*32 + qj][kk], g = gk/9, kk = gk%9
__global__ void prep_wdcn(const float* __restrict__ w, unsigned short* __restrict__ wt3) {
    int i = blockIdx.x * 256 + threadIdx.x;   // i < 72*8192 = 589824
    int slice = i >> 13, rem = i & 8191;
    int oc = rem >> 5, qj = rem & 31;
    int ks = slice & 1, gk = slice >> 1;
    int g = gk / 9, kk = gk % 9;
    int cin = g * 64 + ks * 32 + qj;
    wt3[i] = f16bits(w[(size_t)oc * 2304 + cin * 9 + kk]);
}

// ---------------------------------------------------------------------------
// K1: om conv via f16 MFMA -- ROW-TILED HALO STAGING.
// One block = (batch, row h, 100-px half). Per 64-ch K-chunk: stage the
// 3-row x 102-col halo ONCE into LDS (zero-filled borders), then run all
// 9 taps x 2 ks as shifted LDS reads. 9x less staging, 8 barriers/block.
// Waves: (wv&3) -> oc quarter, (wv>>2) -> px tiles {0-3} / {4-6}.
// R8 bugfix: stage ALL 8 16B-units per (row,col) (64 ch), not 4 (32 ch).
__global__ __launch_bounds__(512, 6) void om_mfma(const unsigned short* __restrict__ xT,
                                                  const unsigned short* __restrict__ wom3,
                                                  const float* __restrict__ bom,
                                                  float* __restrict__ om) {
    __shared__ __align__(16) unsigned short vtile[3][114][72];  // 49248 B -> 3 blocks/CU

    int t = threadIdx.x;
    int lane = t & 63, n16 = t & 15, quad = (lane >> 4) & 3, wv = t >> 6;
    int ocbase = (wv & 3) * 32;
    int wh = wv >> 2;                      // 0: tiles 0-3 (px 0-63), 1: tiles 4-6 (px 64-99+pad)

    int bid = xcd_swizzle(blockIdx.x, 800);   // 2 b * 200 h * 2 halves
    int b = bid / 400, rem0 = bid - b * 400;
    int h = rem0 >> 1, hf = rem0 & 1;
    int c0 = hf * 100;
    const unsigned short* xtb = xT + (size_t)b * NPIX * CIN;

    floatx4 acc[2][4];
#pragma unroll
    for (int i = 0; i < 2; i++)
#pragma unroll
        for (int j = 0; j < 4; j++) acc[i][j] = (floatx4){0.f, 0.f, 0.f, 0.f};

    for (int chunk = 0; chunk < 4; chunk++) {
        if (chunk) __syncthreads();        // prev MFMA readers done before overwrite

        // ---- stage 3 rows x 114 cols x 64 ch (8x 16B units), zero-filled halo/pad ----
        for (int k = 0; k < 6; k++) {
            int L = t + k * 512;           // 2736 units of 16 B (3 * 114 * 8)
            if (L < 2736) {
                int r3 = L / 912, r2 = L - r3 * 912;   // 912 = 114 * 8
                int cc = r2 >> 3, u16 = r2 & 7;
                int gr = h - 1 + r3, gc = c0 - 1 + cc;
                float4 v = {0.f, 0.f, 0.f, 0.f};
                if ((unsigned)gr < (unsigned)HH && (unsigned)gc < (unsigned)WW && cc < 102)
                    v = *(const float4*)(xtb + (size_t)(gr * WW + gc) * CIN + chunk * 64 + u16 * 8);
                *(float4*)&vtile[r3][cc][u16 * 8] = v;
            }
        }
        __syncthreads();

        // ---- 9 taps x 2 ks from LDS ----
#pragma unroll 3
        for (int tap = 0; tap < 9; tap++) {
            int r3 = tap / 3, dj = tap - r3 * 3;
            int colb = dj + wh * 64 + n16;
#pragma unroll
            for (int ks = 0; ks < 2; ks++) {
                int ch = ks * 32 + quad * 8;
                f16x8 bf0 = *(const f16x8*)&vtile[r3][colb     ][ch];
                f16x8 bf1 = *(const f16x8*)&vtile[r3][colb + 16][ch];
                f16x8 bf2 = *(const f16x8*)&vtile[r3][colb + 32][ch];
                const unsigned short* wb = wom3 + (size_t)((tap * 4 + chunk) * 2 + ks) * 4096
                                           + (ocbase + n16) * 32 + quad * 8;
                f16x8 a0 = *(const f16x8*)wb;
                f16x8 a1 = *(const f16x8*)(wb + 512);   // +16 oc
                acc[0][0] = __builtin_amdgcn_mfma_f32_16x16x32_f16(a0, bf0, acc[0][0], 0, 0, 0);
                acc[1][0] = __builtin_amdgcn_mfma_f32_16x16x32_f16(a1, bf0, acc[1][0], 0, 0, 0);
                acc[0][1] = __builtin_amdgcn_mfma_f32_16x16x32_f16(a0, bf1, acc[0][1], 0, 0, 0);
                acc[1][1] = __builtin_amdgcn_mfma_f32_16x16x32_f16(a1, bf1, acc[1][1], 0, 0, 0);
                acc[0][2] = __builtin_amdgcn_mfma_f32_16x16x32_f16(a0, bf2, acc[0][2], 0, 0, 0);
                acc[1][2] = __builtin_amdgcn_mfma_f32_16x16x32_f16(a1, bf2, acc[1][2], 0, 0, 0);
                if (wh == 0) {
                    f16x8 bf3 = *(const f16x8*)&vtile[r3][colb + 48][ch];
                    acc[0][3] = __builtin_amdgcn_mfma_f32_16x16x32_f16(a0, bf3, acc[0][3], 0, 0, 0);
                    acc[1][3] = __builtin_amdgcn_mfma_f32_16x16x32_f16(a1, bf3, acc[1][3], 0, 0, 0);
                }
            }
        }
    }

    // ---- epilogue: D col = n16 (pixel-in-tile), row = quad*4+r (oc); + bias ----
    int hbase = h * WW + c0;
#pragma unroll
    for (int oi = 0; oi < 2; oi++) {
        int oc0 = ocbase + oi * 16 + quad * 4;
        if (oc0 < OMCH) {
#pragma unroll
            for (int tile = 0; tile < 4; tile++) {
                if (wh && tile == 3) continue;            // half-1 has 3 tiles
                int pl = (wh * 4 + tile) * 16 + n16;      // local px 0..111
                if (pl < 100) {
#pragma unroll
                    for (int r = 0; r < 4; r++) {
                        int oc = oc0 + r;
                        if (oc < OMCH)
                            om[((size_t)(b * OMCH + oc)) * NPIX + hbase + pl]
                                = acc[oi][tile][r] + bom[oc];
                    }
                }
            }
        }
    }
}

// ---------------------------------------------------------------------------
// K2: fused DCN. 512 thr / 8 waves, 64 px/block. Wave wv -> oc [32wv, +32).
// Params packed to 12 B/record in LDS (46 KB total -> 3 blocks/CU).
// Pipeline: parm(gk+2) LDS-read || gather(gk+1) || MFMA(gk) || pack(gk+1).
// XCD-chunked block swizzle; wt3 A-fragment-contiguous; bilinear pack in
// packed-f16 VALU (v_pk_fma_f16) -- no scalar converts.
__global__ __launch_bounds__(512, 6) void dcn_mfma(const unsigned short* __restrict__ xT,
                                                   const float* __restrict__ om,
                                                   const unsigned short* __restrict__ wt3,
                                                   float* __restrict__ out) {
    __shared__ unsigned int iPk[36 * 64];                    //  9216 B: i00 | dx1<<16 | dy1<<17
    __shared__ uint2        wPk[36 * 64];                    // 18432 B: 4 x f16 corner weights
    __shared__ __align__(16) unsigned short vbuf[2][64][72]; // 18432 B

    int t = threadIdx.x;
    int l = t & 63;
    int oct = t >> 6;             // wave id
    int p8 = l >> 3;              // pixel sub-index within wave
    int chunk = l & 7;            // 16B channel chunk
    int mypix = oct * 8 + p8;     // staging pixel 0..63
    int n16 = t & 15, quad = l >> 4;
    int ocbase = oct * 32;

    int gp0 = xcd_swizzle(blockIdx.x, 1250) * 64;  // 1250 blocks; 40000 % 64 == 0
    int b = gp0 / NPIX;
    int pix0 = gp0 - b * NPIX;
    const unsigned short* xtb = xT + (size_t)b * NPIX * CIN;
    const float* omb = om + (size_t)b * OMCH * NPIX;

    // ---- prologue: packed sampling params for all (gk, p) ----
    for (int r = t; r < 36 * 64; r += 512) {
        int gk = r >> 6, p = r & 63;
        int g = gk / 9, kk = gk % 9;
        int ki = kk / 3, kj = kk % 3;
        int pp = pix0 + p;
        int hh = pp / WW, ww2 = pp % WW;
        float dy = omb[(size_t)(g * 18 + 2 * kk    ) * NPIX + pp];
        float dx = omb[(size_t)(g * 18 + 2 * kk + 1) * NPIX + pp];
        float mr = omb[(size_t)(72 + g * 9 + kk    ) * NPIX + pp];
        float m = 1.f / (1.f + __expf(-mr));
        float py = (float)(hh - 1 + ki) + dy;
        float px = (float)(ww2 - 1 + kj) + dx;
        float fy = floorf(py), fx = floorf(px);
        float wy = py - fy, wx = px - fx;
        int y0 = (int)fy, x0 = (int)fx, y1 = y0 + 1, x1 = x0 + 1;
        bool vy0 = (y0 >= 0) && (y0 < HH), vy1 = (y1 >= 0) && (y1 < HH);
        bool vx0 = (x0 >= 0) && (x0 < WW), vx1 = (x1 >= 0) && (x1 < WW);
        int cy0 = min(max(y0, 0), HH - 1), cy1 = min(max(y1, 0), HH - 1);
        int cx0 = min(max(x0, 0), WW - 1), cx1 = min(max(x1, 0), WW - 1);
        float w00 = (vy0 && vx0) ? (1.f - wy) * (1.f - wx) * m : 0.f;
        float w01 = (vy0 && vx1) ? (1.f - wy) * wx * m : 0.f;
        float w10 = (vy1 && vx0) ? wy * (1.f - wx) * m : 0.f;
        float w11 = (vy1 && vx1) ? wy * wx * m : 0.f;
        int i00 = cy0 * WW + cx0;
        unsigned int dx1 = (unsigned int)(cx1 - cx0);   // 0/1
        unsigned int dy1 = (unsigned int)(cy1 - cy0);   // 0/1
        iPk[r] = (unsigned int)i00 | (dx1 << 16) | (dy1 << 17);
        uint2 wp;
        wp.x = (unsigned int)f16bits(w00) | ((unsigned int)f16bits(w01) << 16);
        wp.y = (unsigned int)f16bits(w10) | ((unsigned int)f16bits(w11) << 16);
        wPk[r] = wp;
    }
    __syncthreads();

    floatx4 acc[2][4];
#pragma unroll
    for (int i = 0; i < 2; i++)
#pragma unroll
        for (int j = 0; j < 4; j++) acc[i][j] = (floatx4){0.f, 0.f, 0.f, 0.f};

    unsigned int ipNext; uint2 wpNext;   // params for the NEXT gather iteration

    // ---- stage gk = 0 (and preload parm(1)) ----
    {
        unsigned int ip = iPk[mypix];
        uint2 wp = wPk[mypix];
        int i00 = ip & 0xffff;
        int dx1 = (ip >> 16) & 1, dy1 = (ip >> 17) & 1;
        int i01 = i00 + dx1, i10 = i00 + dy1 * WW, i11 = i10 + dx1;
        const unsigned short* xg = xtb + chunk * 8;     // g = 0
        f16x8 c00 = *(const f16x8*)(xg + (size_t)i00 * CIN);
        f16x8 c01 = *(const f16x8*)(xg + (size_t)i01 * CIN);
        f16x8 c10 = *(const f16x8*)(xg + (size_t)i10 * CIN);
        f16x8 c11 = *(const f16x8*)(xg + (size_t)i11 * CIN);
        ipNext = iPk[64 + mypix];
        wpNext = wPk[64 + mypix];
        f16x8 v = c00 * f16lo(wp.x) + c01 * f16hi(wp.x)
                + c10 * f16lo(wp.y) + c11 * f16hi(wp.y);
        *(float4*)&vbuf[0][mypix][chunk * 8] = __builtin_bit_cast(float4, v);
    }
    __syncthreads();

    for (int gk = 0; gk < 36; gk++) {
        int cur = gk & 1;
        bool have = (gk < 35);

        // --- gather gk+1 using pre-loaded params (addresses register-ready) ---
        _Float16 nw00, nw01, nw10, nw11;
        f16x8 n00, n01, n10, n11;
        if (have) {
            unsigned int ip = ipNext; uint2 wp = wpNext;
            int i00 = ip & 0xffff;
            int dx1 = (ip >> 16) & 1, dy1 = (ip >> 17) & 1;
            int i01 = i00 + dx1, i10 = i00 + dy1 * WW, i11 = i10 + dx1;
            const unsigned short* xg = xtb + ((gk + 1) / 9) * 64 + chunk * 8;
            n00 = *(const f16x8*)(xg + (size_t)i00 * CIN);
            n01 = *(const f16x8*)(xg + (size_t)i01 * CIN);
            n10 = *(const f16x8*)(xg + (size_t)i10 * CIN);
            n11 = *(const f16x8*)(xg + (size_t)i11 * CIN);
            nw00 = f16lo(wp.x); nw01 = f16hi(wp.x);
            nw10 = f16lo(wp.y); nw11 = f16hi(wp.y);
        }
        // --- preload params for gk+2 (decoupled from next iter's gather) ---
        if (gk < 34) {
            ipNext = iPk[(gk + 2) * 64 + mypix];
            wpNext = wPk[(gk + 2) * 64 + mypix];
        }

        // --- MFMA phase (gk); weights from wt3: slice (gk*2+ks), contiguous a-loads ---
#pragma unroll
        for (int ks = 0; ks < 2; ks++) {
            f16x8 bf0 = *(const f16x8*)&vbuf[cur][n16     ][ks * 32 + quad * 8];
            f16x8 bf1 = *(const f16x8*)&vbuf[cur][16 + n16][ks * 32 + quad * 8];
            f16x8 bf2 = *(const f16x8*)&vbuf[cur][32 + n16][ks * 32 + quad * 8];
            f16x8 bf3 = *(const f16x8*)&vbuf[cur][48 + n16][ks * 32 + quad * 8];
#pragma unroll
            for (int oi = 0; oi < 2; oi++) {
                f16x8 a = *(const f16x8*)&wt3[(size_t)(gk * 2 + ks) * 8192
                                              + (ocbase + oi * 16 + n16) * 32 + quad * 8];
                acc[oi][0] = __builtin_amdgcn_mfma_f32_16x16x32_f16(a, bf0, acc[oi][0], 0, 0, 0);
                acc[oi][1] = __builtin_amdgcn_mfma_f32_16x16x32_f16(a, bf1, acc[oi][1], 0, 0, 0);
                acc[oi][2] = __builtin_amdgcn_mfma_f32_16x16x32_f16(a, bf2, acc[oi][2], 0, 0, 0);
                acc[oi][3] = __builtin_amdgcn_mfma_f32_16x16x32_f16(a, bf3, acc[oi][3], 0, 0, 0);
            }
        }

        if (have) {
            f16x8 v = n00 * nw00 + n01 * nw01 + n10 * nw10 + n11 * nw11;
            *(float4*)&vbuf[cur ^ 1][mypix][chunk * 8] = __builtin_bit_cast(float4, v);
            __syncthreads();
        }
    }

    // ---- epilogue: ReLU + store ----
#pragma unroll
    for (int oi = 0; oi < 2; oi++)
#pragma unroll
        for (int pt = 0; pt < 4; pt++) {
            int gpix = pix0 + pt * 16 + n16;
#pragma unroll
            for (int r = 0; r < 4; r++) {
                int oc = ocbase + oi * 16 + quad * 4 + r;
                out[((size_t)(b * OCH + oc)) * NPIX + gpix] = fmaxf(acc[oi][pt][r], 0.f);
            }
        }
}

// ---------------------------------------------------------------------------
extern "C" void kernel_launch(void* const* d_in, const int* in_sizes, int n_in,
                              void* d_out, int out_size, void* d_ws, size_t ws_size,
                              hipStream_t stream) {
    const float* x     = (const float*)d_in[0];
    const float* w_om  = (const float*)d_in[1];
    const float* b_om  = (const float*)d_in[2];
    const float* w_dcn = (const float*)d_in[3];
    float* out = (float*)d_out;

    // workspace layout (77.3 MB total)
    char* ws = (char*)d_ws;
    float*          om   = (float*)(ws);                         // 34,560,000 B
    unsigned short* xT   = (unsigned short*)(ws + 34560000);     // 40,960,000 B
    unsigned short* wom3 = (unsigned short*)(ws + 75520000);     //    589,824 B
    unsigned short* wt3  = (unsigned short*)(ws + 76109824);     //  1,179,648 B

    transpose_x<<<1250, 256, 0, stream>>>(x, xT);
    prep_wom   <<<1152, 256, 0, stream>>>(w_om, wom3);
    prep_wdcn  <<<2304, 256, 0, stream>>>(w_dcn, wt3);
    om_mfma    <<< 800, 512, 0, stream>>>(xT, wom3, b_om, om);
    dcn_mfma   <<<1250, 512, 0, stream>>>(xT, om, wt3, out);
}